// Round 1
// baseline (334.465 us; speedup 1.0000x reference)
//
#include <hip/hip_runtime.h>
#include <math.h>

// Problem constants (from reference)
#define N_IMG 2
#define R_PROP 256
#define G_GT 64
#define C_CH 1024
#define FH 50
#define FW 80
#define P_POOL 14
#define NCLS 80
#define IMG_W_F 1280.0f
#define IMG_H_F 800.0f
#define SCALE_F 0.0625f
#define SCORE_TH_F 0.05f
#define NMS_TH_F 0.5f
#define IOU_TH_F 0.5f
#define MAX_DET_I 100
#define SCALE_CLAMP_F 4.135166556742356f  // log(1000/16)

// ---------------------------------------------------------------------------
// Kernel 1: proposal<->gt matching (pairwise IoU argmax over gt axis)
// ---------------------------------------------------------------------------
__global__ __launch_bounds__(256) void match_kernel(
    const float* __restrict__ proposals,  // (N,R,4)
    const float* __restrict__ gt_boxes,   // (N,G,4)
    float* __restrict__ out_idx,          // (N,R) as float
    float* __restrict__ out_lbl) {        // (N,R) as float
  int t = blockIdx.x * blockDim.x + threadIdx.x;
  if (t >= N_IMG * R_PROP) return;
  int n = t / R_PROP;
  const float* pb = proposals + (size_t)t * 4;
  float bx1 = pb[0], by1 = pb[1], bx2 = pb[2], by2 = pb[3];
  float area_b = (bx2 - bx1) * (by2 - by1);
  float best = -1.0f;
  int bidx = 0;
  const float* gt = gt_boxes + (size_t)n * G_GT * 4;
  for (int g = 0; g < G_GT; ++g) {
    float gx1 = gt[g * 4 + 0], gy1 = gt[g * 4 + 1];
    float gx2 = gt[g * 4 + 2], gy2 = gt[g * 4 + 3];
    float area_a = (gx2 - gx1) * (gy2 - gy1);
    float ix1 = fmaxf(gx1, bx1), iy1 = fmaxf(gy1, by1);
    float ix2 = fminf(gx2, bx2), iy2 = fminf(gy2, by2);
    float iw = fmaxf(ix2 - ix1, 0.0f), ih = fmaxf(iy2 - iy1, 0.0f);
    float inter = iw * ih;
    float iou = inter / fmaxf(area_a + area_b - inter, 1e-9f);
    if (iou > best) { best = iou; bidx = g; }  // strict > keeps first occurrence
  }
  out_idx[t] = (float)bidx;
  out_lbl[t] = (best >= IOU_TH_F) ? 1.0f : 0.0f;
}

// ---------------------------------------------------------------------------
// Kernel 2: ROI-align (P=14, S=1) fused with spatial mean -> feat_vec (N*R, C)
// One block per proposal; thread t owns channels [4t, 4t+4) as float4.
// ---------------------------------------------------------------------------
__global__ __launch_bounds__(256) void roi_kernel(
    const float* __restrict__ features,   // (N, FH, FW, C)
    const float* __restrict__ proposals,  // (N, R, 4)
    float* __restrict__ feat_vec) {       // (N*R, C)
  const int blk = blockIdx.x;           // n*R + r
  const int n = blk >> 8;               // R = 256
  const float* feat = features + (size_t)n * (FH * FW * C_CH);
  const int t = threadIdx.x;

  __shared__ float s_ly[P_POOL], s_lx[P_POOL];
  __shared__ int s_y0[P_POOL], s_y1[P_POOL], s_x0[P_POOL], s_x1[P_POOL];

  if (t < 2 * P_POOL) {
    const float* pb = proposals + (size_t)blk * 4;
    bool isY = t < P_POOL;
    int i = isY ? t : t - P_POOL;
    float lo = isY ? pb[1] : pb[0];
    float hi = isY ? pb[3] : pb[2];
    float limit = isY ? (float)(FH - 1) : (float)(FW - 1);
    float b1 = lo * SCALE_F, b2 = hi * SCALE_F;
    float bs = (b2 - b1) * (1.0f / P_POOL);
    float g = b1 + ((float)i + 0.5f) * bs - 0.5f;
    g = fminf(fmaxf(g, 0.0f), limit);
    float fl = floorf(g);
    int i0 = (int)fl;
    int i1 = min(i0 + 1, (int)limit);
    if (isY) { s_y0[i] = i0; s_y1[i] = i1; s_ly[i] = g - fl; }
    else     { s_x0[i] = i0; s_x1[i] = i1; s_lx[i] = g - fl; }
  }
  __syncthreads();

  float4 acc = make_float4(0.f, 0.f, 0.f, 0.f);
  for (int py = 0; py < P_POOL; ++py) {
    float wy1 = s_ly[py], wy0 = 1.0f - wy1;
    const float4* r0 = (const float4*)(feat + (size_t)s_y0[py] * (FW * C_CH)) + t;
    const float4* r1 = (const float4*)(feat + (size_t)s_y1[py] * (FW * C_CH)) + t;
#pragma unroll 7
    for (int px = 0; px < P_POOL; ++px) {
      float wx1v = s_lx[px], wx0v = 1.0f - wx1v;
      int o0 = s_x0[px] * (C_CH / 4);
      int o1 = s_x1[px] * (C_CH / 4);
      float4 f00 = r0[o0];
      float4 f01 = r0[o1];
      float4 f10 = r1[o0];
      float4 f11 = r1[o1];
      float w00 = wy0 * wx0v, w01 = wy0 * wx1v;
      float w10 = wy1 * wx0v, w11 = wy1 * wx1v;
      acc.x += w00 * f00.x + w01 * f01.x + w10 * f10.x + w11 * f11.x;
      acc.y += w00 * f00.y + w01 * f01.y + w10 * f10.y + w11 * f11.y;
      acc.z += w00 * f00.z + w01 * f01.z + w10 * f10.z + w11 * f11.z;
      acc.w += w00 * f00.w + w01 * f01.w + w10 * f10.w + w11 * f11.w;
    }
  }
  const float inv = 1.0f / (float)(P_POOL * P_POOL);
  float4* out = (float4*)(feat_vec + (size_t)blk * C_CH) + t;
  *out = make_float4(acc.x * inv, acc.y * inv, acc.z * inv, acc.w * inv);
}

// ---------------------------------------------------------------------------
// Kernel 3: linear heads + softmax fg-score + box decode. One block/proposal.
// ---------------------------------------------------------------------------
__global__ __launch_bounds__(128) void heads_kernel(
    const float* __restrict__ feat_vec,   // (N*R, C)
    const float* __restrict__ proposals,  // (N, R, 4)
    const float* __restrict__ W_cls,      // (C, 81)
    const float* __restrict__ b_cls,      // (81)
    const float* __restrict__ W_box,      // (C, 4)
    const float* __restrict__ b_box,      // (4)
    float* __restrict__ boxes_dec,        // (N*R, 4)
    float* __restrict__ scores) {         // (N*R)
  const int blk = blockIdx.x;
  const int t = threadIdx.x;
  __shared__ float sf[C_CH];
  __shared__ float sl[85];

  const float4* fv = (const float4*)(feat_vec + (size_t)blk * C_CH);
#pragma unroll
  for (int i = 0; i < 2; ++i) {
    ((float4*)sf)[t + i * 128] = fv[t + i * 128];
  }
  __syncthreads();

  if (t < 85) {
    float acc;
    if (t < 81) {
      acc = b_cls[t];
      for (int k = 0; k < C_CH; ++k) acc += sf[k] * W_cls[k * 81 + t];
    } else {
      int j = t - 81;
      acc = b_box[j];
      for (int k = 0; k < C_CH; ++k) acc += sf[k] * W_box[k * 4 + j];
    }
    sl[t] = acc;
  }
  __syncthreads();

  if (t == 0) {
    float m = sl[0];
    for (int j = 1; j < 81; ++j) m = fmaxf(m, sl[j]);
    float sum = 0.0f, fgm = -INFINITY;
    for (int j = 0; j < 81; ++j) {
      sum += expf(sl[j] - m);
      if (j < NCLS) fgm = fmaxf(fgm, sl[j]);
    }
    float fg = expf(fgm - m) / sum;
    scores[blk] = fg;

    const float* pb = proposals + (size_t)blk * 4;
    float w = pb[2] - pb[0], h = pb[3] - pb[1];
    float cx = pb[0] + 0.5f * w, cy = pb[1] + 0.5f * h;
    float dx = sl[81] / 10.0f;
    float dy = sl[82] / 10.0f;
    float dw = fminf(sl[83] / 5.0f, SCALE_CLAMP_F);
    float dh = fminf(sl[84] / 5.0f, SCALE_CLAMP_F);
    float pcx = dx * w + cx, pcy = dy * h + cy;
    float pw = expf(dw) * w, ph = expf(dh) * h;
    float ox1 = fminf(fmaxf(pcx - 0.5f * pw, 0.0f), IMG_W_F);
    float oy1 = fminf(fmaxf(pcy - 0.5f * ph, 0.0f), IMG_H_F);
    float ox2 = fminf(fmaxf(pcx + 0.5f * pw, 0.0f), IMG_W_F);
    float oy2 = fminf(fmaxf(pcy + 0.5f * ph, 0.0f), IMG_H_F);
    float* bd = boxes_dec + (size_t)blk * 4;
    bd[0] = ox1; bd[1] = oy1; bd[2] = ox2; bd[3] = oy2;
  }
}

// ---------------------------------------------------------------------------
// Kernel 4: greedy NMS + score filter + top-100 rank + det write.
// One block per image. Bitmask NMS: parallel IoU-matrix -> 256-bit masks,
// one serial greedy pass on thread 0 (no per-iteration barriers).
// ---------------------------------------------------------------------------
__global__ __launch_bounds__(256) void nms_kernel(
    const float* __restrict__ boxes_dec,  // (N*R, 4)
    const float* __restrict__ scores,     // (N*R)
    float* __restrict__ det) {            // (N, R, 6)
  const int n = blockIdx.x;
  const int t = threadIdx.x;
  __shared__ float4 sb[R_PROP];                 // sorted boxes
  __shared__ float ss[R_PROP];                  // scores, original order
  __shared__ unsigned long long s_mask[R_PROP * 4];
  __shared__ unsigned long long s_keep[4];
  __shared__ float sm[R_PROP];                  // masked scores, original order

  float4 myb = ((const float4*)boxes_dec)[n * R_PROP + t];
  float mys = scores[n * R_PROP + t];
  ss[t] = mys;
  __syncthreads();

  // stable descending rank (ties by original index)
  int rk = 0;
  for (int j = 0; j < R_PROP; ++j) {
    float sj = ss[j];
    rk += (sj > mys) || (sj == mys && j < t);
  }
  sb[rk] = myb;
  __syncthreads();

  // phase 1: thread t computes IoU bitmask of sorted box t vs all sorted j
  float4 bi = sb[t];
  float area_i = (bi.z - bi.x) * (bi.w - bi.y);
  unsigned long long m0 = 0, m1 = 0, m2 = 0, m3 = 0;
  for (int j = 0; j < R_PROP; ++j) {
    float4 bj = sb[j];
    float area_j = (bj.z - bj.x) * (bj.w - bj.y);
    float ix1 = fmaxf(bi.x, bj.x), iy1 = fmaxf(bi.y, bj.y);
    float ix2 = fminf(bi.z, bj.z), iy2 = fminf(bi.w, bj.w);
    float iw = fmaxf(ix2 - ix1, 0.0f), ih = fmaxf(iy2 - iy1, 0.0f);
    float inter = iw * ih;
    float iou = inter / fmaxf(area_i + area_j - inter, 1e-9f);
    if (iou > NMS_TH_F) {
      unsigned long long bit = 1ull << (j & 63);
      if ((j >> 6) == 0) m0 |= bit;
      else if ((j >> 6) == 1) m1 |= bit;
      else if ((j >> 6) == 2) m2 |= bit;
      else m3 |= bit;
    }
  }
  s_mask[t * 4 + 0] = m0; s_mask[t * 4 + 1] = m1;
  s_mask[t * 4 + 2] = m2; s_mask[t * 4 + 3] = m3;
  __syncthreads();

  // phase 2: serial greedy pass over sorted order
  if (t == 0) {
    unsigned long long k0 = ~0ull, k1 = ~0ull, k2 = ~0ull, k3 = ~0ull;
    for (int i = 1; i < R_PROP; ++i) {
      const unsigned long long* mi = &s_mask[i * 4];
      int w = i >> 6, b = i & 63;
      unsigned long long low_w = (b == 0) ? 0ull : ((1ull << b) - 1ull);
      unsigned long long sup = 0;
      if (w > 0) sup |= mi[0] & k0;
      if (w > 1) sup |= mi[1] & k1;
      if (w > 2) sup |= mi[2] & k2;
      unsigned long long kw = (w == 0) ? k0 : (w == 1) ? k1 : (w == 2) ? k2 : k3;
      sup |= mi[w] & kw & low_w;
      if (sup) {
        unsigned long long clear = ~(1ull << b);
        if (w == 0) k0 &= clear;
        else if (w == 1) k1 &= clear;
        else if (w == 2) k2 &= clear;
        else k3 &= clear;
      }
    }
    s_keep[0] = k0; s_keep[1] = k1; s_keep[2] = k2; s_keep[3] = k3;
  }
  __syncthreads();

  bool kept = (s_keep[rk >> 6] >> (rk & 63)) & 1ull;
  kept = kept && (mys > SCORE_TH_F);
  sm[t] = kept ? mys : -INFINITY;
  __syncthreads();

  float mym = kept ? mys : -INFINITY;
  int rk2 = 0;
  for (int j = 0; j < R_PROP; ++j) {
    float mj = sm[j];
    rk2 += (mj > mym) || (mj == mym && j < t);
  }
  kept = kept && (rk2 < MAX_DET_I);

  float* dr = det + ((size_t)n * R_PROP + t) * 6;
  dr[0] = myb.x; dr[1] = myb.y; dr[2] = myb.z; dr[3] = myb.w;
  dr[4] = mys;
  dr[5] = kept ? 1.0f : 0.0f;
}

// ---------------------------------------------------------------------------
extern "C" void kernel_launch(void* const* d_in, const int* in_sizes, int n_in,
                              void* d_out, int out_size, void* d_ws, size_t ws_size,
                              hipStream_t stream) {
  const float* features  = (const float*)d_in[0];  // (2,50,80,1024)
  const float* proposals = (const float*)d_in[1];  // (2,256,4)
  const float* gt_boxes  = (const float*)d_in[2];  // (2,64,4)
  // d_in[3] gt_classes: unused by reference outputs
  const float* W_cls = (const float*)d_in[4];      // (1024,81)
  const float* b_cls = (const float*)d_in[5];      // (81)
  const float* W_box = (const float*)d_in[6];      // (1024,4)
  const float* b_box = (const float*)d_in[7];      // (4)

  float* out = (float*)d_out;
  // out layout: det [0,3072) | matched_idxs [3072,3584) | match_labels [3584,4096)
  float* out_det = out;
  float* out_idx = out + N_IMG * R_PROP * 6;
  float* out_lbl = out_idx + N_IMG * R_PROP;

  // workspace layout
  float* feat_vec  = (float*)d_ws;                         // 512*1024 floats
  float* boxes_dec = feat_vec + (size_t)N_IMG * R_PROP * C_CH;  // 512*4
  float* scores    = boxes_dec + (size_t)N_IMG * R_PROP * 4;    // 512

  match_kernel<<<2, 256, 0, stream>>>(proposals, gt_boxes, out_idx, out_lbl);
  roi_kernel<<<N_IMG * R_PROP, 256, 0, stream>>>(features, proposals, feat_vec);
  heads_kernel<<<N_IMG * R_PROP, 128, 0, stream>>>(feat_vec, proposals, W_cls, b_cls,
                                                   W_box, b_box, boxes_dec, scores);
  nms_kernel<<<N_IMG, 256, 0, stream>>>(boxes_dec, scores, out_det);
}

// Round 2
// 272.219 us; speedup vs baseline: 1.2287x; 1.2287x over previous
//
#include <hip/hip_runtime.h>
#include <math.h>

// Problem constants (from reference)
#define N_IMG 2
#define R_PROP 256
#define G_GT 64
#define C_CH 1024
#define FH 50
#define FW 80
#define P_POOL 14
#define NCLS 80
#define IMG_W_F 1280.0f
#define IMG_H_F 800.0f
#define SCALE_F 0.0625f
#define SCORE_TH_F 0.05f
#define NMS_TH_F 0.5f
#define IOU_TH_F 0.5f
#define MAX_DET_I 100
#define SCALE_CLAMP_F 4.135166556742356f  // log(1000/16)

// ---------------------------------------------------------------------------
// Kernel 1: proposal<->gt matching (pairwise IoU argmax over gt axis)
// ---------------------------------------------------------------------------
__global__ __launch_bounds__(256) void match_kernel(
    const float* __restrict__ proposals,  // (N,R,4)
    const float* __restrict__ gt_boxes,   // (N,G,4)
    float* __restrict__ out_idx,          // (N,R) as float
    float* __restrict__ out_lbl) {        // (N,R) as float
  int t = blockIdx.x * blockDim.x + threadIdx.x;
  if (t >= N_IMG * R_PROP) return;
  int n = t / R_PROP;
  const float* pb = proposals + (size_t)t * 4;
  float bx1 = pb[0], by1 = pb[1], bx2 = pb[2], by2 = pb[3];
  float area_b = (bx2 - bx1) * (by2 - by1);
  float best = -1.0f;
  int bidx = 0;
  const float* gt = gt_boxes + (size_t)n * G_GT * 4;
#pragma unroll 4
  for (int g = 0; g < G_GT; ++g) {
    float gx1 = gt[g * 4 + 0], gy1 = gt[g * 4 + 1];
    float gx2 = gt[g * 4 + 2], gy2 = gt[g * 4 + 3];
    float area_a = (gx2 - gx1) * (gy2 - gy1);
    float ix1 = fmaxf(gx1, bx1), iy1 = fmaxf(gy1, by1);
    float ix2 = fminf(gx2, bx2), iy2 = fminf(gy2, by2);
    float iw = fmaxf(ix2 - ix1, 0.0f), ih = fmaxf(iy2 - iy1, 0.0f);
    float inter = iw * ih;
    float iou = inter / fmaxf(area_a + area_b - inter, 1e-9f);
    if (iou > best) { best = iou; bidx = g; }  // strict > keeps first occurrence
  }
  out_idx[t] = (float)bidx;
  out_lbl[t] = (best >= IOU_TH_F) ? 1.0f : 0.0f;
}

// ---------------------------------------------------------------------------
// Kernel 2: separable ROI-align (P=14, S=1) + spatial mean -> feat_vec (N*R,C)
// Exact reformulation: cell weight factorizes, w(y,x) = Wy[y] * Wx[x] where
// Wy[y] = sum over py of its bilinear row contribution. Each distinct feature
// cell is loaded ONCE (avg ~11x11 cells) instead of 784 corner loads.
// One block per proposal; thread t owns channels [4t, 4t+4) as float4.
// ---------------------------------------------------------------------------
__global__ __launch_bounds__(256) void roi_kernel(
    const float* __restrict__ features,   // (N, FH, FW, C)
    const float* __restrict__ proposals,  // (N, R, 4)
    float* __restrict__ feat_vec) {       // (N*R, C)
  const int blk = blockIdx.x;           // n*R + r
  const int n = blk >> 8;               // R = 256
  const float* feat = features + (size_t)n * (FH * FW * C_CH);
  const int t = threadIdx.x;

  __shared__ float s_Wy[FH];
  __shared__ float s_Wx[FW];
  __shared__ int s_b[4];  // y_lo, y_hi, x_lo, x_hi

  if (t < FH) s_Wy[t] = 0.0f;
  if (t < FW) s_Wx[t] = 0.0f;
  __syncthreads();

  if (t < 2 * P_POOL) {
    const float* pb = proposals + (size_t)blk * 4;
    bool isY = t < P_POOL;
    int i = isY ? t : t - P_POOL;
    float lo = isY ? pb[1] : pb[0];
    float hi = isY ? pb[3] : pb[2];
    float limit = isY ? (float)(FH - 1) : (float)(FW - 1);
    float b1 = lo * SCALE_F, b2 = hi * SCALE_F;
    float bs = (b2 - b1) * (1.0f / P_POOL);
    float g = b1 + ((float)i + 0.5f) * bs - 0.5f;
    g = fminf(fmaxf(g, 0.0f), limit);
    float fl = floorf(g);
    int i0 = (int)fl;
    int i1 = min(i0 + 1, (int)limit);
    float l = g - fl;
    if (isY) {
      atomicAdd(&s_Wy[i0], 1.0f - l);
      atomicAdd(&s_Wy[i1], l);
      if (i == 0) s_b[0] = i0;
      if (i == P_POOL - 1) s_b[1] = i1;
    } else {
      atomicAdd(&s_Wx[i0], 1.0f - l);
      atomicAdd(&s_Wx[i1], l);
      if (i == 0) s_b[2] = i0;
      if (i == P_POOL - 1) s_b[3] = i1;
    }
  }
  __syncthreads();

  const int ylo = s_b[0], yhi = s_b[1], xlo = s_b[2], xhi = s_b[3];
  float4 acc = make_float4(0.f, 0.f, 0.f, 0.f);
  for (int y = ylo; y <= yhi; ++y) {
    float wy = s_Wy[y];
    const float4* row = (const float4*)(feat + (size_t)y * (FW * C_CH)) + t;
#pragma unroll 4
    for (int x = xlo; x <= xhi; ++x) {
      float w = wy * s_Wx[x];
      float4 f = row[x * (C_CH / 4)];
      acc.x += w * f.x;
      acc.y += w * f.y;
      acc.z += w * f.z;
      acc.w += w * f.w;
    }
  }
  const float inv = 1.0f / (float)(P_POOL * P_POOL);
  float4* out = (float4*)(feat_vec + (size_t)blk * C_CH) + t;
  *out = make_float4(acc.x * inv, acc.y * inv, acc.z * inv, acc.w * inv);
}

// ---------------------------------------------------------------------------
// Kernel 3: linear heads + softmax fg-score + box decode. One block/proposal.
// ---------------------------------------------------------------------------
__global__ __launch_bounds__(128) void heads_kernel(
    const float* __restrict__ feat_vec,   // (N*R, C)
    const float* __restrict__ proposals,  // (N, R, 4)
    const float* __restrict__ W_cls,      // (C, 81)
    const float* __restrict__ b_cls,      // (81)
    const float* __restrict__ W_box,      // (C, 4)
    const float* __restrict__ b_box,      // (4)
    float* __restrict__ boxes_dec,        // (N*R, 4)
    float* __restrict__ scores) {         // (N*R)
  const int blk = blockIdx.x;
  const int t = threadIdx.x;
  __shared__ float sf[C_CH];
  __shared__ float sl[85];

  const float4* fv = (const float4*)(feat_vec + (size_t)blk * C_CH);
#pragma unroll
  for (int i = 0; i < 2; ++i) {
    ((float4*)sf)[t + i * 128] = fv[t + i * 128];
  }
  __syncthreads();

  if (t < 85) {
    float acc;
    if (t < 81) {
      acc = b_cls[t];
#pragma unroll 8
      for (int k = 0; k < C_CH; ++k) acc += sf[k] * W_cls[k * 81 + t];
    } else {
      int j = t - 81;
      acc = b_box[j];
#pragma unroll 8
      for (int k = 0; k < C_CH; ++k) acc += sf[k] * W_box[k * 4 + j];
    }
    sl[t] = acc;
  }
  __syncthreads();

  if (t == 0) {
    float m = sl[0];
    for (int j = 1; j < 81; ++j) m = fmaxf(m, sl[j]);
    float sum = 0.0f, fgm = -INFINITY;
    for (int j = 0; j < 81; ++j) {
      sum += expf(sl[j] - m);
      if (j < NCLS) fgm = fmaxf(fgm, sl[j]);
    }
    float fg = expf(fgm - m) / sum;
    scores[blk] = fg;

    const float* pb = proposals + (size_t)blk * 4;
    float w = pb[2] - pb[0], h = pb[3] - pb[1];
    float cx = pb[0] + 0.5f * w, cy = pb[1] + 0.5f * h;
    float dx = sl[81] / 10.0f;
    float dy = sl[82] / 10.0f;
    float dw = fminf(sl[83] / 5.0f, SCALE_CLAMP_F);
    float dh = fminf(sl[84] / 5.0f, SCALE_CLAMP_F);
    float pcx = dx * w + cx, pcy = dy * h + cy;
    float pw = expf(dw) * w, ph = expf(dh) * h;
    float ox1 = fminf(fmaxf(pcx - 0.5f * pw, 0.0f), IMG_W_F);
    float oy1 = fminf(fmaxf(pcy - 0.5f * ph, 0.0f), IMG_H_F);
    float ox2 = fminf(fmaxf(pcx + 0.5f * pw, 0.0f), IMG_W_F);
    float oy2 = fminf(fmaxf(pcy + 0.5f * ph, 0.0f), IMG_H_F);
    float* bd = boxes_dec + (size_t)blk * 4;
    bd[0] = ox1; bd[1] = oy1; bd[2] = ox2; bd[3] = oy2;
  }
}

// ---------------------------------------------------------------------------
// Kernel 4: greedy NMS + score filter + top-100 rank + det write.
// One block per image, 1024 threads: thread u = q*256+i handles box i,
// quarter q of every O(R) scan (64 iterations instead of 256). Bitmask NMS
// with one serial 256-step greedy pass on thread 0 (unrolled; static LDS
// addresses let loads pipeline ahead of the bit-op chain).
// ---------------------------------------------------------------------------
__global__ __launch_bounds__(1024) void nms_kernel(
    const float* __restrict__ boxes_dec,  // (N*R, 4)
    const float* __restrict__ scores,     // (N*R)
    float* __restrict__ det) {            // (N, R, 6)
  const int n = blockIdx.x;
  const int u = threadIdx.x;
  const int i = u & 255;
  const int q = u >> 8;           // 0..3
  const int j0 = q * 64;

  __shared__ float ss[R_PROP];                  // scores, original order
  __shared__ float4 sbs[R_PROP];                // sorted boxes
  __shared__ int s_part[4 * R_PROP];            // partial rank counts
  __shared__ int s_rank[R_PROP];
  __shared__ unsigned long long s_mask[R_PROP * 4];
  __shared__ unsigned long long s_keep[4];
  __shared__ float sm[R_PROP];                  // masked scores, original order

  float4 myb;
  float mys;
  if (q == 0) {
    myb = ((const float4*)boxes_dec)[n * R_PROP + i];
    mys = scores[n * R_PROP + i];
    ss[i] = mys;
  }
  __syncthreads();

  // stable descending rank (ties by original index), split 4 ways over j
  {
    float s = ss[i];
    int cnt = 0;
#pragma unroll 8
    for (int j = j0; j < j0 + 64; ++j) {
      float sj = ss[j];
      cnt += (sj > s) || (sj == s && j < i);
    }
    s_part[q * R_PROP + i] = cnt;
  }
  __syncthreads();
  if (q == 0) {
    int rk = s_part[i] + s_part[R_PROP + i] + s_part[2 * R_PROP + i] +
             s_part[3 * R_PROP + i];
    s_rank[i] = rk;
    sbs[rk] = myb;
  }
  __syncthreads();

  // phase 1: thread (i,q) computes mask word q of sorted box i vs sorted j
  {
    float4 bi = sbs[i];
    float area_i = (bi.z - bi.x) * (bi.w - bi.y);
    unsigned long long m = 0;
#pragma unroll 8
    for (int jj = 0; jj < 64; ++jj) {
      int j = j0 + jj;
      float4 bj = sbs[j];
      float area_j = (bj.z - bj.x) * (bj.w - bj.y);
      float ix1 = fmaxf(bi.x, bj.x), iy1 = fmaxf(bi.y, bj.y);
      float ix2 = fminf(bi.z, bj.z), iy2 = fminf(bi.w, bj.w);
      float iw = fmaxf(ix2 - ix1, 0.0f), ih = fmaxf(iy2 - iy1, 0.0f);
      float inter = iw * ih;
      float iou = inter / fmaxf(area_i + area_j - inter, 1e-9f);
      m |= (iou > NMS_TH_F) ? (1ull << jj) : 0ull;
    }
    s_mask[i * 4 + q] = m;
  }
  __syncthreads();

  // phase 2: serial greedy pass over sorted order (thread 0)
  if (u == 0) {
    unsigned long long k0 = ~0ull, k1 = ~0ull, k2 = ~0ull, k3 = ~0ull;
#pragma unroll 8
    for (int ii = 1; ii < R_PROP; ++ii) {
      const unsigned long long* mi = &s_mask[ii * 4];
      int w = ii >> 6, b = ii & 63;
      unsigned long long low_w = (b == 0) ? 0ull : ((1ull << b) - 1ull);
      unsigned long long sup = 0;
      if (w > 0) sup |= mi[0] & k0;
      if (w > 1) sup |= mi[1] & k1;
      if (w > 2) sup |= mi[2] & k2;
      unsigned long long kw = (w == 0) ? k0 : (w == 1) ? k1 : (w == 2) ? k2 : k3;
      sup |= mi[w] & kw & low_w;
      if (sup) {
        unsigned long long clear = ~(1ull << b);
        if (w == 0) k0 &= clear;
        else if (w == 1) k1 &= clear;
        else if (w == 2) k2 &= clear;
        else k3 &= clear;
      }
    }
    s_keep[0] = k0; s_keep[1] = k1; s_keep[2] = k2; s_keep[3] = k3;
  }
  __syncthreads();

  bool kept = false;
  if (q == 0) {
    int rk = s_rank[i];
    kept = ((s_keep[rk >> 6] >> (rk & 63)) & 1ull) && (mys > SCORE_TH_F);
    sm[i] = kept ? mys : -INFINITY;
  }
  __syncthreads();

  // top-100 rank over masked scores, split 4 ways
  {
    float mym = sm[i];
    int cnt = 0;
#pragma unroll 8
    for (int j = j0; j < j0 + 64; ++j) {
      float mj = sm[j];
      cnt += (mj > mym) || (mj == mym && j < i);
    }
    s_part[q * R_PROP + i] = cnt;
  }
  __syncthreads();

  if (q == 0) {
    int rk2 = s_part[i] + s_part[R_PROP + i] + s_part[2 * R_PROP + i] +
              s_part[3 * R_PROP + i];
    kept = kept && (rk2 < MAX_DET_I);
    float* dr = det + ((size_t)n * R_PROP + i) * 6;
    dr[0] = myb.x; dr[1] = myb.y; dr[2] = myb.z; dr[3] = myb.w;
    dr[4] = mys;
    dr[5] = kept ? 1.0f : 0.0f;
  }
}

// ---------------------------------------------------------------------------
extern "C" void kernel_launch(void* const* d_in, const int* in_sizes, int n_in,
                              void* d_out, int out_size, void* d_ws, size_t ws_size,
                              hipStream_t stream) {
  const float* features  = (const float*)d_in[0];  // (2,50,80,1024)
  const float* proposals = (const float*)d_in[1];  // (2,256,4)
  const float* gt_boxes  = (const float*)d_in[2];  // (2,64,4)
  // d_in[3] gt_classes: unused by reference outputs
  const float* W_cls = (const float*)d_in[4];      // (1024,81)
  const float* b_cls = (const float*)d_in[5];      // (81)
  const float* W_box = (const float*)d_in[6];      // (1024,4)
  const float* b_box = (const float*)d_in[7];      // (4)

  float* out = (float*)d_out;
  // out layout: det [0,3072) | matched_idxs [3072,3584) | match_labels [3584,4096)
  float* out_det = out;
  float* out_idx = out + N_IMG * R_PROP * 6;
  float* out_lbl = out_idx + N_IMG * R_PROP;

  // workspace layout
  float* feat_vec  = (float*)d_ws;                              // 512*1024
  float* boxes_dec = feat_vec + (size_t)N_IMG * R_PROP * C_CH;  // 512*4
  float* scores    = boxes_dec + (size_t)N_IMG * R_PROP * 4;    // 512

  match_kernel<<<2, 256, 0, stream>>>(proposals, gt_boxes, out_idx, out_lbl);
  roi_kernel<<<N_IMG * R_PROP, 256, 0, stream>>>(features, proposals, feat_vec);
  heads_kernel<<<N_IMG * R_PROP, 128, 0, stream>>>(feat_vec, proposals, W_cls, b_cls,
                                                   W_box, b_box, boxes_dec, scores);
  nms_kernel<<<N_IMG, 1024, 0, stream>>>(boxes_dec, scores, out_det);
}

// Round 3
// 227.850 us; speedup vs baseline: 1.4679x; 1.1947x over previous
//
#include <hip/hip_runtime.h>
#include <math.h>

// Problem constants (from reference)
#define N_IMG 2
#define R_PROP 256
#define G_GT 64
#define C_CH 1024
#define FH 50
#define FW 80
#define P_POOL 14
#define NCLS 80
#define IMG_W_F 1280.0f
#define IMG_H_F 800.0f
#define SCALE_F 0.0625f
#define SCORE_TH_F 0.05f
#define NMS_TH_F 0.5f
#define IOU_TH_F 0.5f
#define MAX_DET_I 100
#define SCALE_CLAMP_F 4.135166556742356f  // log(1000/16)

// ---------------------------------------------------------------------------
// Kernel 1: proposal<->gt matching (pairwise IoU argmax over gt axis)
// ---------------------------------------------------------------------------
__global__ __launch_bounds__(256) void match_kernel(
    const float* __restrict__ proposals,  // (N,R,4)
    const float* __restrict__ gt_boxes,   // (N,G,4)
    float* __restrict__ out_idx,          // (N,R) as float
    float* __restrict__ out_lbl) {        // (N,R) as float
  int t = blockIdx.x * blockDim.x + threadIdx.x;
  if (t >= N_IMG * R_PROP) return;
  int n = t / R_PROP;
  const float* pb = proposals + (size_t)t * 4;
  float bx1 = pb[0], by1 = pb[1], bx2 = pb[2], by2 = pb[3];
  float area_b = (bx2 - bx1) * (by2 - by1);
  float best = -1.0f;
  int bidx = 0;
  const float* gt = gt_boxes + (size_t)n * G_GT * 4;
#pragma unroll 4
  for (int g = 0; g < G_GT; ++g) {
    float gx1 = gt[g * 4 + 0], gy1 = gt[g * 4 + 1];
    float gx2 = gt[g * 4 + 2], gy2 = gt[g * 4 + 3];
    float area_a = (gx2 - gx1) * (gy2 - gy1);
    float ix1 = fmaxf(gx1, bx1), iy1 = fmaxf(gy1, by1);
    float ix2 = fminf(gx2, bx2), iy2 = fminf(gy2, by2);
    float iw = fmaxf(ix2 - ix1, 0.0f), ih = fmaxf(iy2 - iy1, 0.0f);
    float inter = iw * ih;
    float iou = inter / fmaxf(area_a + area_b - inter, 1e-9f);
    if (iou > best) { best = iou; bidx = g; }  // strict > keeps first occurrence
  }
  out_idx[t] = (float)bidx;
  out_lbl[t] = (best >= IOU_TH_F) ? 1.0f : 0.0f;
}

// ---------------------------------------------------------------------------
// Kernel 2: separable ROI-align (P=14, S=1) + spatial mean -> feat_vec (N*R,C)
// Exact reformulation: cell weight factorizes, w(y,x) = Wy[y] * Wx[x] where
// Wy[y] = sum over py of its bilinear row contribution. Each distinct feature
// cell is loaded ONCE (avg ~11x11 cells) instead of 784 corner loads.
// One block per proposal; thread t owns channels [4t, 4t+4) as float4.
// ---------------------------------------------------------------------------
__global__ __launch_bounds__(256) void roi_kernel(
    const float* __restrict__ features,   // (N, FH, FW, C)
    const float* __restrict__ proposals,  // (N, R, 4)
    float* __restrict__ feat_vec) {       // (N*R, C)
  const int blk = blockIdx.x;           // n*R + r
  const int n = blk >> 8;               // R = 256
  const float* feat = features + (size_t)n * (FH * FW * C_CH);
  const int t = threadIdx.x;

  __shared__ float s_Wy[FH];
  __shared__ float s_Wx[FW];
  __shared__ int s_b[4];  // y_lo, y_hi, x_lo, x_hi

  if (t < FH) s_Wy[t] = 0.0f;
  if (t < FW) s_Wx[t] = 0.0f;
  __syncthreads();

  if (t < 2 * P_POOL) {
    const float* pb = proposals + (size_t)blk * 4;
    bool isY = t < P_POOL;
    int i = isY ? t : t - P_POOL;
    float lo = isY ? pb[1] : pb[0];
    float hi = isY ? pb[3] : pb[2];
    float limit = isY ? (float)(FH - 1) : (float)(FW - 1);
    float b1 = lo * SCALE_F, b2 = hi * SCALE_F;
    float bs = (b2 - b1) * (1.0f / P_POOL);
    float g = b1 + ((float)i + 0.5f) * bs - 0.5f;
    g = fminf(fmaxf(g, 0.0f), limit);
    float fl = floorf(g);
    int i0 = (int)fl;
    int i1 = min(i0 + 1, (int)limit);
    float l = g - fl;
    if (isY) {
      atomicAdd(&s_Wy[i0], 1.0f - l);
      atomicAdd(&s_Wy[i1], l);
      if (i == 0) s_b[0] = i0;
      if (i == P_POOL - 1) s_b[1] = i1;
    } else {
      atomicAdd(&s_Wx[i0], 1.0f - l);
      atomicAdd(&s_Wx[i1], l);
      if (i == 0) s_b[2] = i0;
      if (i == P_POOL - 1) s_b[3] = i1;
    }
  }
  __syncthreads();

  const int ylo = s_b[0], yhi = s_b[1], xlo = s_b[2], xhi = s_b[3];
  float4 acc = make_float4(0.f, 0.f, 0.f, 0.f);
  for (int y = ylo; y <= yhi; ++y) {
    float wy = s_Wy[y];
    const float4* row = (const float4*)(feat + (size_t)y * (FW * C_CH)) + t;
#pragma unroll 4
    for (int x = xlo; x <= xhi; ++x) {
      float w = wy * s_Wx[x];
      float4 f = row[x * (C_CH / 4)];
      acc.x += w * f.x;
      acc.y += w * f.y;
      acc.z += w * f.z;
      acc.w += w * f.w;
    }
  }
  const float inv = 1.0f / (float)(P_POOL * P_POOL);
  float4* out = (float4*)(feat_vec + (size_t)blk * C_CH) + t;
  *out = make_float4(acc.x * inv, acc.y * inv, acc.z * inv, acc.w * inv);
}

// ---------------------------------------------------------------------------
// Kernel 3: linear heads + softmax fg-score + box decode. One block/proposal,
// 512 threads. Thread u = kq*85 + j (kq<6) computes a partial dot of output
// column j over k in {kq, kq+6, ...} -> 6-way shorter serial-load chain.
// Partials reduced in LDS; softmax via shuffle reductions (no serial loops).
// ---------------------------------------------------------------------------
__global__ __launch_bounds__(512) void heads_kernel(
    const float* __restrict__ feat_vec,   // (N*R, C)
    const float* __restrict__ proposals,  // (N, R, 4)
    const float* __restrict__ W_cls,      // (C, 81)
    const float* __restrict__ b_cls,      // (81)
    const float* __restrict__ W_box,      // (C, 4)
    const float* __restrict__ b_box,      // (4)
    float* __restrict__ boxes_dec,        // (N*R, 4)
    float* __restrict__ scores) {         // (N*R)
  const int blk = blockIdx.x;
  const int u = threadIdx.x;
  __shared__ float sf[C_CH];
  __shared__ float s_part[6][85];
  __shared__ float sl[85];
  __shared__ float s_red[8];

  // stage feat row: 512 threads x float2 = 1024 floats
  ((float2*)sf)[u] = ((const float2*)(feat_vec + (size_t)blk * C_CH))[u];
  __syncthreads();

  const int kq = u / 85;        // 0..6 (u=510,511 -> 6, inactive)
  const int j = u - kq * 85;
  if (kq < 6) {
    float acc = 0.0f;
    if (j < 81) {
      const float* __restrict__ w = W_cls + j;
#pragma unroll 8
      for (int k = kq; k < C_CH; k += 6) acc += sf[k] * w[k * 81];
    } else {
      const float* __restrict__ w = W_box + (j - 81);
#pragma unroll 8
      for (int k = kq; k < C_CH; k += 6) acc += sf[k] * w[k * 4];
    }
    s_part[kq][j] = acc;
  }
  __syncthreads();

  if (u < 85) {
    float acc = (u < 81) ? b_cls[u] : b_box[u - 81];
#pragma unroll
    for (int p = 0; p < 6; ++p) acc += s_part[p][u];
    sl[u] = acc;
  }
  __syncthreads();

  // parallel reductions over the 81 logits (2 waves cover 0..127)
  if (u < 128) {
    float xm = (u < 81) ? sl[u] : -INFINITY;        // max over all 81
    float xf = (u < NCLS) ? sl[u] : -INFINITY;      // max over fg 80
#pragma unroll
    for (int off = 32; off; off >>= 1) {
      xm = fmaxf(xm, __shfl_down(xm, off, 64));
      xf = fmaxf(xf, __shfl_down(xf, off, 64));
    }
    if ((u & 63) == 0) { s_red[u >> 6] = xm; s_red[2 + (u >> 6)] = xf; }
  }
  __syncthreads();
  const float m = fmaxf(s_red[0], s_red[1]);
  if (u < 128) {
    float xs = (u < 81) ? expf(sl[u] - m) : 0.0f;
#pragma unroll
    for (int off = 32; off; off >>= 1) xs += __shfl_down(xs, off, 64);
    if ((u & 63) == 0) s_red[4 + (u >> 6)] = xs;
  }
  __syncthreads();

  if (u == 0) {
    float sum = s_red[4] + s_red[5];
    float fgm = fmaxf(s_red[2], s_red[3]);
    scores[blk] = expf(fgm - m) / sum;

    const float* pb = proposals + (size_t)blk * 4;
    float w = pb[2] - pb[0], h = pb[3] - pb[1];
    float cx = pb[0] + 0.5f * w, cy = pb[1] + 0.5f * h;
    float dx = sl[81] * 0.1f;
    float dy = sl[82] * 0.1f;
    float dw = fminf(sl[83] * 0.2f, SCALE_CLAMP_F);
    float dh = fminf(sl[84] * 0.2f, SCALE_CLAMP_F);
    float pcx = dx * w + cx, pcy = dy * h + cy;
    float pw = expf(dw) * w, ph = expf(dh) * h;
    float ox1 = fminf(fmaxf(pcx - 0.5f * pw, 0.0f), IMG_W_F);
    float oy1 = fminf(fmaxf(pcy - 0.5f * ph, 0.0f), IMG_H_F);
    float ox2 = fminf(fmaxf(pcx + 0.5f * pw, 0.0f), IMG_W_F);
    float oy2 = fminf(fmaxf(pcy + 0.5f * ph, 0.0f), IMG_H_F);
    float* bd = boxes_dec + (size_t)blk * 4;
    bd[0] = ox1; bd[1] = oy1; bd[2] = ox2; bd[3] = oy2;
  }
}

// ---------------------------------------------------------------------------
// Kernel 4: greedy NMS + score filter + top-100 rank + det write.
// One block per image, 1024 threads: thread u = q*256+i handles box i,
// quarter q of every O(R) scan. Bitmask NMS with one serial greedy pass.
// ---------------------------------------------------------------------------
__global__ __launch_bounds__(1024) void nms_kernel(
    const float* __restrict__ boxes_dec,  // (N*R, 4)
    const float* __restrict__ scores,     // (N*R)
    float* __restrict__ det) {            // (N, R, 6)
  const int n = blockIdx.x;
  const int u = threadIdx.x;
  const int i = u & 255;
  const int q = u >> 8;           // 0..3
  const int j0 = q * 64;

  __shared__ float ss[R_PROP];                  // scores, original order
  __shared__ float4 sbs[R_PROP];                // sorted boxes
  __shared__ int s_part[4 * R_PROP];            // partial rank counts
  __shared__ int s_rank[R_PROP];
  __shared__ unsigned long long s_mask[R_PROP * 4];
  __shared__ unsigned long long s_keep[4];
  __shared__ float sm[R_PROP];                  // masked scores, original order

  float4 myb;
  float mys;
  if (q == 0) {
    myb = ((const float4*)boxes_dec)[n * R_PROP + i];
    mys = scores[n * R_PROP + i];
    ss[i] = mys;
  }
  __syncthreads();

  // stable descending rank (ties by original index), split 4 ways over j
  {
    float s = ss[i];
    int cnt = 0;
#pragma unroll 8
    for (int j = j0; j < j0 + 64; ++j) {
      float sj = ss[j];
      cnt += (sj > s) || (sj == s && j < i);
    }
    s_part[q * R_PROP + i] = cnt;
  }
  __syncthreads();
  if (q == 0) {
    int rk = s_part[i] + s_part[R_PROP + i] + s_part[2 * R_PROP + i] +
             s_part[3 * R_PROP + i];
    s_rank[i] = rk;
    sbs[rk] = myb;
  }
  __syncthreads();

  // phase 1: thread (i,q) computes mask word q of sorted box i vs sorted j
  {
    float4 bi = sbs[i];
    float area_i = (bi.z - bi.x) * (bi.w - bi.y);
    unsigned long long m = 0;
#pragma unroll 8
    for (int jj = 0; jj < 64; ++jj) {
      int j = j0 + jj;
      float4 bj = sbs[j];
      float area_j = (bj.z - bj.x) * (bj.w - bj.y);
      float ix1 = fmaxf(bi.x, bj.x), iy1 = fmaxf(bi.y, bj.y);
      float ix2 = fminf(bi.z, bj.z), iy2 = fminf(bi.w, bj.w);
      float iw = fmaxf(ix2 - ix1, 0.0f), ih = fmaxf(iy2 - iy1, 0.0f);
      float inter = iw * ih;
      float iou = inter / fmaxf(area_i + area_j - inter, 1e-9f);
      m |= (iou > NMS_TH_F) ? (1ull << jj) : 0ull;
    }
    s_mask[i * 4 + q] = m;
  }
  __syncthreads();

  // phase 2: serial greedy pass over sorted order (thread 0)
  if (u == 0) {
    unsigned long long k0 = ~0ull, k1 = ~0ull, k2 = ~0ull, k3 = ~0ull;
#pragma unroll 8
    for (int ii = 1; ii < R_PROP; ++ii) {
      const unsigned long long* mi = &s_mask[ii * 4];
      int w = ii >> 6, b = ii & 63;
      unsigned long long low_w = (b == 0) ? 0ull : ((1ull << b) - 1ull);
      unsigned long long sup = 0;
      if (w > 0) sup |= mi[0] & k0;
      if (w > 1) sup |= mi[1] & k1;
      if (w > 2) sup |= mi[2] & k2;
      unsigned long long kw = (w == 0) ? k0 : (w == 1) ? k1 : (w == 2) ? k2 : k3;
      sup |= mi[w] & kw & low_w;
      if (sup) {
        unsigned long long clear = ~(1ull << b);
        if (w == 0) k0 &= clear;
        else if (w == 1) k1 &= clear;
        else if (w == 2) k2 &= clear;
        else k3 &= clear;
      }
    }
    s_keep[0] = k0; s_keep[1] = k1; s_keep[2] = k2; s_keep[3] = k3;
  }
  __syncthreads();

  bool kept = false;
  if (q == 0) {
    int rk = s_rank[i];
    kept = ((s_keep[rk >> 6] >> (rk & 63)) & 1ull) && (mys > SCORE_TH_F);
    sm[i] = kept ? mys : -INFINITY;
  }
  __syncthreads();

  // top-100 rank over masked scores, split 4 ways
  {
    float mym = sm[i];
    int cnt = 0;
#pragma unroll 8
    for (int j = j0; j < j0 + 64; ++j) {
      float mj = sm[j];
      cnt += (mj > mym) || (mj == mym && j < i);
    }
    s_part[q * R_PROP + i] = cnt;
  }
  __syncthreads();

  if (q == 0) {
    int rk2 = s_part[i] + s_part[R_PROP + i] + s_part[2 * R_PROP + i] +
              s_part[3 * R_PROP + i];
    kept = kept && (rk2 < MAX_DET_I);
    float* dr = det + ((size_t)n * R_PROP + i) * 6;
    dr[0] = myb.x; dr[1] = myb.y; dr[2] = myb.z; dr[3] = myb.w;
    dr[4] = mys;
    dr[5] = kept ? 1.0f : 0.0f;
  }
}

// ---------------------------------------------------------------------------
extern "C" void kernel_launch(void* const* d_in, const int* in_sizes, int n_in,
                              void* d_out, int out_size, void* d_ws, size_t ws_size,
                              hipStream_t stream) {
  const float* features  = (const float*)d_in[0];  // (2,50,80,1024)
  const float* proposals = (const float*)d_in[1];  // (2,256,4)
  const float* gt_boxes  = (const float*)d_in[2];  // (2,64,4)
  // d_in[3] gt_classes: unused by reference outputs
  const float* W_cls = (const float*)d_in[4];      // (1024,81)
  const float* b_cls = (const float*)d_in[5];      // (81)
  const float* W_box = (const float*)d_in[6];      // (1024,4)
  const float* b_box = (const float*)d_in[7];      // (4)

  float* out = (float*)d_out;
  // out layout: det [0,3072) | matched_idxs [3072,3584) | match_labels [3584,4096)
  float* out_det = out;
  float* out_idx = out + N_IMG * R_PROP * 6;
  float* out_lbl = out_idx + N_IMG * R_PROP;

  // workspace layout
  float* feat_vec  = (float*)d_ws;                              // 512*1024
  float* boxes_dec = feat_vec + (size_t)N_IMG * R_PROP * C_CH;  // 512*4
  float* scores    = boxes_dec + (size_t)N_IMG * R_PROP * 4;    // 512

  match_kernel<<<2, 256, 0, stream>>>(proposals, gt_boxes, out_idx, out_lbl);
  roi_kernel<<<N_IMG * R_PROP, 256, 0, stream>>>(features, proposals, feat_vec);
  heads_kernel<<<N_IMG * R_PROP, 512, 0, stream>>>(feat_vec, proposals, W_cls, b_cls,
                                                   W_box, b_box, boxes_dec, scores);
  nms_kernel<<<N_IMG, 1024, 0, stream>>>(boxes_dec, scores, out_det);
}

// Round 4
// 195.904 us; speedup vs baseline: 1.7073x; 1.1631x over previous
//
#include <hip/hip_runtime.h>
#include <math.h>

// Problem constants (from reference)
#define N_IMG 2
#define R_PROP 256
#define G_GT 64
#define C_CH 1024
#define FH 50
#define FW 80
#define P_POOL 14
#define NCLS 80
#define IMG_W_F 1280.0f
#define IMG_H_F 800.0f
#define SCALE_F 0.0625f
#define SCORE_TH_F 0.05f
#define NMS_TH_F 0.5f
#define IOU_TH_F 0.5f
#define MAX_DET_I 100
#define SCALE_CLAMP_F 4.135166556742356f  // log(1000/16)

// ---------------------------------------------------------------------------
// Kernel 1: proposal<->gt matching (pairwise IoU argmax over gt axis)
// ---------------------------------------------------------------------------
__global__ __launch_bounds__(256) void match_kernel(
    const float* __restrict__ proposals,  // (N,R,4)
    const float* __restrict__ gt_boxes,   // (N,G,4)
    float* __restrict__ out_idx,          // (N,R) as float
    float* __restrict__ out_lbl) {        // (N,R) as float
  int t = blockIdx.x * blockDim.x + threadIdx.x;
  if (t >= N_IMG * R_PROP) return;
  int n = t / R_PROP;
  const float* pb = proposals + (size_t)t * 4;
  float bx1 = pb[0], by1 = pb[1], bx2 = pb[2], by2 = pb[3];
  float area_b = (bx2 - bx1) * (by2 - by1);
  float best = -1.0f;
  int bidx = 0;
  const float* gt = gt_boxes + (size_t)n * G_GT * 4;
#pragma unroll 4
  for (int g = 0; g < G_GT; ++g) {
    float gx1 = gt[g * 4 + 0], gy1 = gt[g * 4 + 1];
    float gx2 = gt[g * 4 + 2], gy2 = gt[g * 4 + 3];
    float area_a = (gx2 - gx1) * (gy2 - gy1);
    float ix1 = fmaxf(gx1, bx1), iy1 = fmaxf(gy1, by1);
    float ix2 = fminf(gx2, bx2), iy2 = fminf(gy2, by2);
    float iw = fmaxf(ix2 - ix1, 0.0f), ih = fmaxf(iy2 - iy1, 0.0f);
    float inter = iw * ih;
    float iou = inter / fmaxf(area_a + area_b - inter, 1e-9f);
    if (iou > best) { best = iou; bidx = g; }  // strict > keeps first occurrence
  }
  out_idx[t] = (float)bidx;
  out_lbl[t] = (best >= IOU_TH_F) ? 1.0f : 0.0f;
}

// ---------------------------------------------------------------------------
// Kernel 2: separable ROI-align (P=14, S=1) + spatial mean -> feat_vec (N*R,C)
// ---------------------------------------------------------------------------
__global__ __launch_bounds__(256) void roi_kernel(
    const float* __restrict__ features,   // (N, FH, FW, C)
    const float* __restrict__ proposals,  // (N, R, 4)
    float* __restrict__ feat_vec) {       // (N*R, C)
  const int blk = blockIdx.x;           // n*R + r
  const int n = blk >> 8;               // R = 256
  const float* feat = features + (size_t)n * (FH * FW * C_CH);
  const int t = threadIdx.x;

  __shared__ float s_Wy[FH];
  __shared__ float s_Wx[FW];
  __shared__ int s_b[4];  // y_lo, y_hi, x_lo, x_hi

  if (t < FH) s_Wy[t] = 0.0f;
  if (t < FW) s_Wx[t] = 0.0f;
  __syncthreads();

  if (t < 2 * P_POOL) {
    const float* pb = proposals + (size_t)blk * 4;
    bool isY = t < P_POOL;
    int i = isY ? t : t - P_POOL;
    float lo = isY ? pb[1] : pb[0];
    float hi = isY ? pb[3] : pb[2];
    float limit = isY ? (float)(FH - 1) : (float)(FW - 1);
    float b1 = lo * SCALE_F, b2 = hi * SCALE_F;
    float bs = (b2 - b1) * (1.0f / P_POOL);
    float g = b1 + ((float)i + 0.5f) * bs - 0.5f;
    g = fminf(fmaxf(g, 0.0f), limit);
    float fl = floorf(g);
    int i0 = (int)fl;
    int i1 = min(i0 + 1, (int)limit);
    float l = g - fl;
    if (isY) {
      atomicAdd(&s_Wy[i0], 1.0f - l);
      atomicAdd(&s_Wy[i1], l);
      if (i == 0) s_b[0] = i0;
      if (i == P_POOL - 1) s_b[1] = i1;
    } else {
      atomicAdd(&s_Wx[i0], 1.0f - l);
      atomicAdd(&s_Wx[i1], l);
      if (i == 0) s_b[2] = i0;
      if (i == P_POOL - 1) s_b[3] = i1;
    }
  }
  __syncthreads();

  const int ylo = s_b[0], yhi = s_b[1], xlo = s_b[2], xhi = s_b[3];
  float4 acc = make_float4(0.f, 0.f, 0.f, 0.f);
  for (int y = ylo; y <= yhi; ++y) {
    float wy = s_Wy[y];
    const float4* row = (const float4*)(feat + (size_t)y * (FW * C_CH)) + t;
#pragma unroll 4
    for (int x = xlo; x <= xhi; ++x) {
      float w = wy * s_Wx[x];
      float4 f = row[x * (C_CH / 4)];
      acc.x += w * f.x;
      acc.y += w * f.y;
      acc.z += w * f.z;
      acc.w += w * f.w;
    }
  }
  const float inv = 1.0f / (float)(P_POOL * P_POOL);
  float4* out = (float4*)(feat_vec + (size_t)blk * C_CH) + t;
  *out = make_float4(acc.x * inv, acc.y * inv, acc.z * inv, acc.w * inv);
}

// ---------------------------------------------------------------------------
// Kernel 3: linear heads + softmax fg-score + box decode. One block/proposal,
// 512 threads, 6-way K-split, shuffle-reduced softmax.
// ---------------------------------------------------------------------------
__global__ __launch_bounds__(512) void heads_kernel(
    const float* __restrict__ feat_vec,   // (N*R, C)
    const float* __restrict__ proposals,  // (N, R, 4)
    const float* __restrict__ W_cls,      // (C, 81)
    const float* __restrict__ b_cls,      // (81)
    const float* __restrict__ W_box,      // (C, 4)
    const float* __restrict__ b_box,      // (4)
    float* __restrict__ boxes_dec,        // (N*R, 4)
    float* __restrict__ scores) {         // (N*R)
  const int blk = blockIdx.x;
  const int u = threadIdx.x;
  __shared__ float sf[C_CH];
  __shared__ float s_part[6][85];
  __shared__ float sl[85];
  __shared__ float s_red[8];

  // stage feat row: 512 threads x float2 = 1024 floats
  ((float2*)sf)[u] = ((const float2*)(feat_vec + (size_t)blk * C_CH))[u];
  __syncthreads();

  const int kq = u / 85;        // 0..6 (u=510,511 -> 6, inactive)
  const int j = u - kq * 85;
  if (kq < 6) {
    float acc = 0.0f;
    if (j < 81) {
      const float* __restrict__ w = W_cls + j;
#pragma unroll 8
      for (int k = kq; k < C_CH; k += 6) acc += sf[k] * w[k * 81];
    } else {
      const float* __restrict__ w = W_box + (j - 81);
#pragma unroll 8
      for (int k = kq; k < C_CH; k += 6) acc += sf[k] * w[k * 4];
    }
    s_part[kq][j] = acc;
  }
  __syncthreads();

  if (u < 85) {
    float acc = (u < 81) ? b_cls[u] : b_box[u - 81];
#pragma unroll
    for (int p = 0; p < 6; ++p) acc += s_part[p][u];
    sl[u] = acc;
  }
  __syncthreads();

  // parallel reductions over the 81 logits (2 waves cover 0..127)
  if (u < 128) {
    float xm = (u < 81) ? sl[u] : -INFINITY;        // max over all 81
    float xf = (u < NCLS) ? sl[u] : -INFINITY;      // max over fg 80
#pragma unroll
    for (int off = 32; off; off >>= 1) {
      xm = fmaxf(xm, __shfl_down(xm, off, 64));
      xf = fmaxf(xf, __shfl_down(xf, off, 64));
    }
    if ((u & 63) == 0) { s_red[u >> 6] = xm; s_red[2 + (u >> 6)] = xf; }
  }
  __syncthreads();
  const float m = fmaxf(s_red[0], s_red[1]);
  if (u < 128) {
    float xs = (u < 81) ? expf(sl[u] - m) : 0.0f;
#pragma unroll
    for (int off = 32; off; off >>= 1) xs += __shfl_down(xs, off, 64);
    if ((u & 63) == 0) s_red[4 + (u >> 6)] = xs;
  }
  __syncthreads();

  if (u == 0) {
    float sum = s_red[4] + s_red[5];
    float fgm = fmaxf(s_red[2], s_red[3]);
    scores[blk] = expf(fgm - m) / sum;

    const float* pb = proposals + (size_t)blk * 4;
    float w = pb[2] - pb[0], h = pb[3] - pb[1];
    float cx = pb[0] + 0.5f * w, cy = pb[1] + 0.5f * h;
    float dx = sl[81] * 0.1f;
    float dy = sl[82] * 0.1f;
    float dw = fminf(sl[83] * 0.2f, SCALE_CLAMP_F);
    float dh = fminf(sl[84] * 0.2f, SCALE_CLAMP_F);
    float pcx = dx * w + cx, pcy = dy * h + cy;
    float pw = expf(dw) * w, ph = expf(dh) * h;
    float ox1 = fminf(fmaxf(pcx - 0.5f * pw, 0.0f), IMG_W_F);
    float oy1 = fminf(fmaxf(pcy - 0.5f * ph, 0.0f), IMG_H_F);
    float ox2 = fminf(fmaxf(pcx + 0.5f * pw, 0.0f), IMG_W_F);
    float oy2 = fminf(fmaxf(pcy + 0.5f * ph, 0.0f), IMG_H_F);
    float* bd = boxes_dec + (size_t)blk * 4;
    bd[0] = ox1; bd[1] = oy1; bd[2] = ox2; bd[3] = oy2;
  }
}

// ---------------------------------------------------------------------------
// Kernel 4: greedy NMS + score filter + top-100 rank + det write.
// One block per image, 1024 threads. Scans are 4-way split with float4 LDS
// loads. The serial greedy pass is BRANCHLESS (cndmask keep-update) with the
// word loop fully unrolled, so the per-iteration LDS mask loads are
// unconditionally issued and pipeline 16-deep ahead of the ALU chain.
// ---------------------------------------------------------------------------
__global__ __launch_bounds__(1024) void nms_kernel(
    const float* __restrict__ boxes_dec,  // (N*R, 4)
    const float* __restrict__ scores,     // (N*R)
    float* __restrict__ det) {            // (N, R, 6)
  const int n = blockIdx.x;
  const int u = threadIdx.x;
  const int i = u & 255;
  const int q = u >> 8;           // 0..3
  const int j40 = q * 16;         // float4 index start for this quarter

  __shared__ __align__(16) float ss[R_PROP];     // scores, original order
  __shared__ float4 sbs[R_PROP];                 // sorted boxes
  __shared__ int s_part[4 * R_PROP];             // partial rank counts
  __shared__ int s_rank[R_PROP];
  __shared__ __align__(16) unsigned long long s_mask[R_PROP * 4];
  __shared__ unsigned long long s_keep[4];
  __shared__ __align__(16) float sm[R_PROP];     // masked scores, orig order

  float4 myb;
  float mys;
  if (q == 0) {
    myb = ((const float4*)boxes_dec)[n * R_PROP + i];
    mys = scores[n * R_PROP + i];
    ss[i] = mys;
  }
  __syncthreads();

  // stable descending rank (ties by original index): float4 loads, 16/thread
  {
    float s = ss[i];
    int cnt = 0;
#pragma unroll
    for (int j4 = j40; j4 < j40 + 16; ++j4) {
      float4 v = ((const float4*)ss)[j4];
      int jb = j4 * 4;
      cnt += (v.x > s) || (v.x == s && jb + 0 < i);
      cnt += (v.y > s) || (v.y == s && jb + 1 < i);
      cnt += (v.z > s) || (v.z == s && jb + 2 < i);
      cnt += (v.w > s) || (v.w == s && jb + 3 < i);
    }
    s_part[q * R_PROP + i] = cnt;
  }
  __syncthreads();
  if (q == 0) {
    int rk = s_part[i] + s_part[R_PROP + i] + s_part[2 * R_PROP + i] +
             s_part[3 * R_PROP + i];
    s_rank[i] = rk;
    sbs[rk] = myb;
  }
  __syncthreads();

  // phase 1: thread (i,q) computes mask word q of sorted box i vs sorted j
  {
    float4 bi = sbs[i];
    float area_i = (bi.z - bi.x) * (bi.w - bi.y);
    unsigned long long m = 0;
    const int j0 = q * 64;
#pragma unroll 8
    for (int jj = 0; jj < 64; ++jj) {
      float4 bj = sbs[j0 + jj];
      float area_j = (bj.z - bj.x) * (bj.w - bj.y);
      float ix1 = fmaxf(bi.x, bj.x), iy1 = fmaxf(bi.y, bj.y);
      float ix2 = fminf(bi.z, bj.z), iy2 = fminf(bi.w, bj.w);
      float iw = fmaxf(ix2 - ix1, 0.0f), ih = fmaxf(iy2 - iy1, 0.0f);
      float inter = iw * ih;
      float iou = inter / fmaxf(area_i + area_j - inter, 1e-9f);
      m |= (iou > NMS_TH_F) ? (1ull << jj) : 0ull;
    }
    s_mask[i * 4 + q] = m;
  }
  __syncthreads();

  // phase 2: branchless serial greedy pass over sorted order (thread 0).
  // Word loop fully unrolled -> per-word code only touches needed mask words;
  // bit loop partially unrolled -> LDS loads issue ahead of the ALU chain.
  if (u == 0) {
    unsigned long long K0 = ~0ull, K1 = ~0ull, K2 = ~0ull, K3 = ~0ull;
    // word 0 (bits 1..63; bit 0 = top box, always kept)
#pragma unroll 16
    for (int b = 1; b < 64; ++b) {
      unsigned long long m0 = s_mask[(size_t)b * 4 + 0];
      unsigned long long sup = m0 & K0 & ((1ull << b) - 1ull);
      K0 = sup ? (K0 & ~(1ull << b)) : K0;
    }
    // word 1
#pragma unroll 16
    for (int b = 0; b < 64; ++b) {
      const unsigned long long* mi = &s_mask[(size_t)(64 + b) * 4];
      unsigned long long m0 = mi[0], m1 = mi[1];
      unsigned long long sup = (m0 & K0) | (m1 & K1 & ((1ull << b) - 1ull));
      K1 = sup ? (K1 & ~(1ull << b)) : K1;
    }
    // word 2
#pragma unroll 16
    for (int b = 0; b < 64; ++b) {
      const unsigned long long* mi = &s_mask[(size_t)(128 + b) * 4];
      unsigned long long m0 = mi[0], m1 = mi[1], m2 = mi[2];
      unsigned long long sup =
          (m0 & K0) | (m1 & K1) | (m2 & K2 & ((1ull << b) - 1ull));
      K2 = sup ? (K2 & ~(1ull << b)) : K2;
    }
    // word 3
#pragma unroll 16
    for (int b = 0; b < 64; ++b) {
      const unsigned long long* mi = &s_mask[(size_t)(192 + b) * 4];
      unsigned long long m0 = mi[0], m1 = mi[1], m2 = mi[2], m3 = mi[3];
      unsigned long long sup = (m0 & K0) | (m1 & K1) | (m2 & K2) |
                               (m3 & K3 & ((1ull << b) - 1ull));
      K3 = sup ? (K3 & ~(1ull << b)) : K3;
    }
    s_keep[0] = K0; s_keep[1] = K1; s_keep[2] = K2; s_keep[3] = K3;
  }
  __syncthreads();

  bool kept = false;
  if (q == 0) {
    int rk = s_rank[i];
    kept = ((s_keep[rk >> 6] >> (rk & 63)) & 1ull) && (mys > SCORE_TH_F);
    sm[i] = kept ? mys : -INFINITY;
  }
  __syncthreads();

  // top-100 rank over masked scores: float4 loads, 16/thread
  {
    float mym = sm[i];
    int cnt = 0;
#pragma unroll
    for (int j4 = j40; j4 < j40 + 16; ++j4) {
      float4 v = ((const float4*)sm)[j4];
      int jb = j4 * 4;
      cnt += (v.x > mym) || (v.x == mym && jb + 0 < i);
      cnt += (v.y > mym) || (v.y == mym && jb + 1 < i);
      cnt += (v.z > mym) || (v.z == mym && jb + 2 < i);
      cnt += (v.w > mym) || (v.w == mym && jb + 3 < i);
    }
    s_part[q * R_PROP + i] = cnt;
  }
  __syncthreads();

  if (q == 0) {
    int rk2 = s_part[i] + s_part[R_PROP + i] + s_part[2 * R_PROP + i] +
              s_part[3 * R_PROP + i];
    kept = kept && (rk2 < MAX_DET_I);
    float* dr = det + ((size_t)n * R_PROP + i) * 6;
    dr[0] = myb.x; dr[1] = myb.y; dr[2] = myb.z; dr[3] = myb.w;
    dr[4] = mys;
    dr[5] = kept ? 1.0f : 0.0f;
  }
}

// ---------------------------------------------------------------------------
extern "C" void kernel_launch(void* const* d_in, const int* in_sizes, int n_in,
                              void* d_out, int out_size, void* d_ws, size_t ws_size,
                              hipStream_t stream) {
  const float* features  = (const float*)d_in[0];  // (2,50,80,1024)
  const float* proposals = (const float*)d_in[1];  // (2,256,4)
  const float* gt_boxes  = (const float*)d_in[2];  // (2,64,4)
  // d_in[3] gt_classes: unused by reference outputs
  const float* W_cls = (const float*)d_in[4];      // (1024,81)
  const float* b_cls = (const float*)d_in[5];      // (81)
  const float* W_box = (const float*)d_in[6];      // (1024,4)
  const float* b_box = (const float*)d_in[7];      // (4)

  float* out = (float*)d_out;
  // out layout: det [0,3072) | matched_idxs [3072,3584) | match_labels [3584,4096)
  float* out_det = out;
  float* out_idx = out + N_IMG * R_PROP * 6;
  float* out_lbl = out_idx + N_IMG * R_PROP;

  // workspace layout
  float* feat_vec  = (float*)d_ws;                              // 512*1024
  float* boxes_dec = feat_vec + (size_t)N_IMG * R_PROP * C_CH;  // 512*4
  float* scores    = boxes_dec + (size_t)N_IMG * R_PROP * 4;    // 512

  match_kernel<<<2, 256, 0, stream>>>(proposals, gt_boxes, out_idx, out_lbl);
  roi_kernel<<<N_IMG * R_PROP, 256, 0, stream>>>(features, proposals, feat_vec);
  heads_kernel<<<N_IMG * R_PROP, 512, 0, stream>>>(feat_vec, proposals, W_cls, b_cls,
                                                   W_box, b_box, boxes_dec, scores);
  nms_kernel<<<N_IMG, 1024, 0, stream>>>(boxes_dec, scores, out_det);
}

// Round 5
// 181.878 us; speedup vs baseline: 1.8390x; 1.0771x over previous
//
#include <hip/hip_runtime.h>
#include <math.h>

// Problem constants (from reference)
#define N_IMG 2
#define R_PROP 256
#define G_GT 64
#define C_CH 1024
#define FH 50
#define FW 80
#define P_POOL 14
#define NCLS 80
#define IMG_W_F 1280.0f
#define IMG_H_F 800.0f
#define SCALE_F 0.0625f
#define SCORE_TH_F 0.05f
#define NMS_TH_F 0.5f
#define IOU_TH_F 0.5f
#define MAX_DET_I 100
#define SCALE_CLAMP_F 4.135166556742356f  // log(1000/16)

// ---------------------------------------------------------------------------
// Kernel 1: proposal<->gt matching (pairwise IoU argmax over gt axis)
// ---------------------------------------------------------------------------
__global__ __launch_bounds__(256) void match_kernel(
    const float* __restrict__ proposals,  // (N,R,4)
    const float* __restrict__ gt_boxes,   // (N,G,4)
    float* __restrict__ out_idx,          // (N,R) as float
    float* __restrict__ out_lbl) {        // (N,R) as float
  int t = blockIdx.x * blockDim.x + threadIdx.x;
  if (t >= N_IMG * R_PROP) return;
  int n = t / R_PROP;
  const float* pb = proposals + (size_t)t * 4;
  float bx1 = pb[0], by1 = pb[1], bx2 = pb[2], by2 = pb[3];
  float area_b = (bx2 - bx1) * (by2 - by1);
  float best = -1.0f;
  int bidx = 0;
  const float* gt = gt_boxes + (size_t)n * G_GT * 4;
#pragma unroll 4
  for (int g = 0; g < G_GT; ++g) {
    float gx1 = gt[g * 4 + 0], gy1 = gt[g * 4 + 1];
    float gx2 = gt[g * 4 + 2], gy2 = gt[g * 4 + 3];
    float area_a = (gx2 - gx1) * (gy2 - gy1);
    float ix1 = fmaxf(gx1, bx1), iy1 = fmaxf(gy1, by1);
    float ix2 = fminf(gx2, bx2), iy2 = fminf(gy2, by2);
    float iw = fmaxf(ix2 - ix1, 0.0f), ih = fmaxf(iy2 - iy1, 0.0f);
    float inter = iw * ih;
    float iou = inter / fmaxf(area_a + area_b - inter, 1e-9f);
    if (iou > best) { best = iou; bidx = g; }  // strict > keeps first occurrence
  }
  out_idx[t] = (float)bidx;
  out_lbl[t] = (best >= IOU_TH_F) ? 1.0f : 0.0f;
}

// ---------------------------------------------------------------------------
// Kernel 2: separable ROI-align (P=14, S=1) + spatial mean -> feat_vec (N*R,C)
// 1024 threads/block: thread (c4 = t&255, g = t>>8) accumulates rows
// y = ylo+g, ylo+g+4, ... for channel slot c4 (float4). Groups 1..3 spill
// partials to LDS; group 0 reduces and stores. 16 waves/block -> 32 waves/CU
// (vs 8 before): 4x the loads in flight and 4x intra-block row parallelism
// to absorb per-proposal cell-count variance (9..441 cells).
// ---------------------------------------------------------------------------
__global__ __launch_bounds__(1024) void roi_kernel(
    const float* __restrict__ features,   // (N, FH, FW, C)
    const float* __restrict__ proposals,  // (N, R, 4)
    float* __restrict__ feat_vec) {       // (N*R, C)
  const int blk = blockIdx.x;           // n*R + r
  const int n = blk >> 8;               // R = 256
  const float* feat = features + (size_t)n * (FH * FW * C_CH);
  const int t = threadIdx.x;
  const int c4 = t & 255;
  const int g = t >> 8;                 // 0..3 row group

  __shared__ float s_Wy[FH];
  __shared__ float s_Wx[FW];
  __shared__ int s_b[4];  // y_lo, y_hi, x_lo, x_hi
  __shared__ float4 s_red[3][256];

  if (t < FH) s_Wy[t] = 0.0f;
  if (t >= 128 && t < 128 + FW) s_Wx[t - 128] = 0.0f;
  __syncthreads();

  if (t < 2 * P_POOL) {
    const float* pb = proposals + (size_t)blk * 4;
    bool isY = t < P_POOL;
    int i = isY ? t : t - P_POOL;
    float lo = isY ? pb[1] : pb[0];
    float hi = isY ? pb[3] : pb[2];
    float limit = isY ? (float)(FH - 1) : (float)(FW - 1);
    float b1 = lo * SCALE_F, b2 = hi * SCALE_F;
    float bs = (b2 - b1) * (1.0f / P_POOL);
    float gg = b1 + ((float)i + 0.5f) * bs - 0.5f;
    gg = fminf(fmaxf(gg, 0.0f), limit);
    float fl = floorf(gg);
    int i0 = (int)fl;
    int i1 = min(i0 + 1, (int)limit);
    float l = gg - fl;
    if (isY) {
      atomicAdd(&s_Wy[i0], 1.0f - l);
      atomicAdd(&s_Wy[i1], l);
      if (i == 0) s_b[0] = i0;
      if (i == P_POOL - 1) s_b[1] = i1;
    } else {
      atomicAdd(&s_Wx[i0], 1.0f - l);
      atomicAdd(&s_Wx[i1], l);
      if (i == 0) s_b[2] = i0;
      if (i == P_POOL - 1) s_b[3] = i1;
    }
  }
  __syncthreads();

  const int ylo = s_b[0], yhi = s_b[1], xlo = s_b[2], xhi = s_b[3];
  float4 acc = make_float4(0.f, 0.f, 0.f, 0.f);
  for (int y = ylo + g; y <= yhi; y += 4) {
    float wy = s_Wy[y];
    const float4* row = (const float4*)(feat + (size_t)y * (FW * C_CH)) + c4;
#pragma unroll 4
    for (int x = xlo; x <= xhi; ++x) {
      float w = wy * s_Wx[x];
      float4 f = row[x * (C_CH / 4)];
      acc.x += w * f.x;
      acc.y += w * f.y;
      acc.z += w * f.z;
      acc.w += w * f.w;
    }
  }
  if (g > 0) s_red[g - 1][c4] = acc;
  __syncthreads();

  if (g == 0) {
    float4 a0 = s_red[0][c4];
    float4 a1 = s_red[1][c4];
    float4 a2 = s_red[2][c4];
    const float inv = 1.0f / (float)(P_POOL * P_POOL);
    float4 r;
    r.x = (acc.x + a0.x + a1.x + a2.x) * inv;
    r.y = (acc.y + a0.y + a1.y + a2.y) * inv;
    r.z = (acc.z + a0.z + a1.z + a2.z) * inv;
    r.w = (acc.w + a0.w + a1.w + a2.w) * inv;
    ((float4*)(feat_vec + (size_t)blk * C_CH))[c4] = r;
  }
}

// ---------------------------------------------------------------------------
// Kernel 3: linear heads + softmax fg-score + box decode. One block/proposal,
// 512 threads, 6-way K-split, shuffle-reduced softmax.
// ---------------------------------------------------------------------------
__global__ __launch_bounds__(512) void heads_kernel(
    const float* __restrict__ feat_vec,   // (N*R, C)
    const float* __restrict__ proposals,  // (N, R, 4)
    const float* __restrict__ W_cls,      // (C, 81)
    const float* __restrict__ b_cls,      // (81)
    const float* __restrict__ W_box,      // (C, 4)
    const float* __restrict__ b_box,      // (4)
    float* __restrict__ boxes_dec,        // (N*R, 4)
    float* __restrict__ scores) {         // (N*R)
  const int blk = blockIdx.x;
  const int u = threadIdx.x;
  __shared__ float sf[C_CH];
  __shared__ float s_part[6][85];
  __shared__ float sl[85];
  __shared__ float s_red[8];

  // stage feat row: 512 threads x float2 = 1024 floats
  ((float2*)sf)[u] = ((const float2*)(feat_vec + (size_t)blk * C_CH))[u];
  __syncthreads();

  const int kq = u / 85;        // 0..6 (u=510,511 -> 6, inactive)
  const int j = u - kq * 85;
  if (kq < 6) {
    float acc = 0.0f;
    if (j < 81) {
      const float* __restrict__ w = W_cls + j;
#pragma unroll 8
      for (int k = kq; k < C_CH; k += 6) acc += sf[k] * w[k * 81];
    } else {
      const float* __restrict__ w = W_box + (j - 81);
#pragma unroll 8
      for (int k = kq; k < C_CH; k += 6) acc += sf[k] * w[k * 4];
    }
    s_part[kq][j] = acc;
  }
  __syncthreads();

  if (u < 85) {
    float acc = (u < 81) ? b_cls[u] : b_box[u - 81];
#pragma unroll
    for (int p = 0; p < 6; ++p) acc += s_part[p][u];
    sl[u] = acc;
  }
  __syncthreads();

  // parallel reductions over the 81 logits (2 waves cover 0..127)
  if (u < 128) {
    float xm = (u < 81) ? sl[u] : -INFINITY;        // max over all 81
    float xf = (u < NCLS) ? sl[u] : -INFINITY;      // max over fg 80
#pragma unroll
    for (int off = 32; off; off >>= 1) {
      xm = fmaxf(xm, __shfl_down(xm, off, 64));
      xf = fmaxf(xf, __shfl_down(xf, off, 64));
    }
    if ((u & 63) == 0) { s_red[u >> 6] = xm; s_red[2 + (u >> 6)] = xf; }
  }
  __syncthreads();
  const float m = fmaxf(s_red[0], s_red[1]);
  if (u < 128) {
    float xs = (u < 81) ? expf(sl[u] - m) : 0.0f;
#pragma unroll
    for (int off = 32; off; off >>= 1) xs += __shfl_down(xs, off, 64);
    if ((u & 63) == 0) s_red[4 + (u >> 6)] = xs;
  }
  __syncthreads();

  if (u == 0) {
    float sum = s_red[4] + s_red[5];
    float fgm = fmaxf(s_red[2], s_red[3]);
    scores[blk] = expf(fgm - m) / sum;

    const float* pb = proposals + (size_t)blk * 4;
    float w = pb[2] - pb[0], h = pb[3] - pb[1];
    float cx = pb[0] + 0.5f * w, cy = pb[1] + 0.5f * h;
    float dx = sl[81] * 0.1f;
    float dy = sl[82] * 0.1f;
    float dw = fminf(sl[83] * 0.2f, SCALE_CLAMP_F);
    float dh = fminf(sl[84] * 0.2f, SCALE_CLAMP_F);
    float pcx = dx * w + cx, pcy = dy * h + cy;
    float pw = expf(dw) * w, ph = expf(dh) * h;
    float ox1 = fminf(fmaxf(pcx - 0.5f * pw, 0.0f), IMG_W_F);
    float oy1 = fminf(fmaxf(pcy - 0.5f * ph, 0.0f), IMG_H_F);
    float ox2 = fminf(fmaxf(pcx + 0.5f * pw, 0.0f), IMG_W_F);
    float oy2 = fminf(fmaxf(pcy + 0.5f * ph, 0.0f), IMG_H_F);
    float* bd = boxes_dec + (size_t)blk * 4;
    bd[0] = ox1; bd[1] = oy1; bd[2] = ox2; bd[3] = oy2;
  }
}

// ---------------------------------------------------------------------------
// Kernel 4: greedy NMS + score filter + top-100 rank + det write.
// One block per image, 1024 threads. Scans are 4-way split with float4 LDS
// loads; serial greedy pass is branchless with unconditional mask loads.
// ---------------------------------------------------------------------------
__global__ __launch_bounds__(1024) void nms_kernel(
    const float* __restrict__ boxes_dec,  // (N*R, 4)
    const float* __restrict__ scores,     // (N*R)
    float* __restrict__ det) {            // (N, R, 6)
  const int n = blockIdx.x;
  const int u = threadIdx.x;
  const int i = u & 255;
  const int q = u >> 8;           // 0..3
  const int j40 = q * 16;         // float4 index start for this quarter

  __shared__ __align__(16) float ss[R_PROP];     // scores, original order
  __shared__ float4 sbs[R_PROP];                 // sorted boxes
  __shared__ int s_part[4 * R_PROP];             // partial rank counts
  __shared__ int s_rank[R_PROP];
  __shared__ __align__(16) unsigned long long s_mask[R_PROP * 4];
  __shared__ unsigned long long s_keep[4];
  __shared__ __align__(16) float sm[R_PROP];     // masked scores, orig order

  float4 myb;
  float mys;
  if (q == 0) {
    myb = ((const float4*)boxes_dec)[n * R_PROP + i];
    mys = scores[n * R_PROP + i];
    ss[i] = mys;
  }
  __syncthreads();

  // stable descending rank (ties by original index): float4 loads, 16/thread
  {
    float s = ss[i];
    int cnt = 0;
#pragma unroll
    for (int j4 = j40; j4 < j40 + 16; ++j4) {
      float4 v = ((const float4*)ss)[j4];
      int jb = j4 * 4;
      cnt += (v.x > s) || (v.x == s && jb + 0 < i);
      cnt += (v.y > s) || (v.y == s && jb + 1 < i);
      cnt += (v.z > s) || (v.z == s && jb + 2 < i);
      cnt += (v.w > s) || (v.w == s && jb + 3 < i);
    }
    s_part[q * R_PROP + i] = cnt;
  }
  __syncthreads();
  if (q == 0) {
    int rk = s_part[i] + s_part[R_PROP + i] + s_part[2 * R_PROP + i] +
             s_part[3 * R_PROP + i];
    s_rank[i] = rk;
    sbs[rk] = myb;
  }
  __syncthreads();

  // phase 1: thread (i,q) computes mask word q of sorted box i vs sorted j
  {
    float4 bi = sbs[i];
    float area_i = (bi.z - bi.x) * (bi.w - bi.y);
    unsigned long long m = 0;
    const int j0 = q * 64;
#pragma unroll 8
    for (int jj = 0; jj < 64; ++jj) {
      float4 bj = sbs[j0 + jj];
      float area_j = (bj.z - bj.x) * (bj.w - bj.y);
      float ix1 = fmaxf(bi.x, bj.x), iy1 = fmaxf(bi.y, bj.y);
      float ix2 = fminf(bi.z, bj.z), iy2 = fminf(bi.w, bj.w);
      float iw = fmaxf(ix2 - ix1, 0.0f), ih = fmaxf(iy2 - iy1, 0.0f);
      float inter = iw * ih;
      float iou = inter / fmaxf(area_i + area_j - inter, 1e-9f);
      m |= (iou > NMS_TH_F) ? (1ull << jj) : 0ull;
    }
    s_mask[i * 4 + q] = m;
  }
  __syncthreads();

  // phase 2: branchless serial greedy pass over sorted order (thread 0).
  if (u == 0) {
    unsigned long long K0 = ~0ull, K1 = ~0ull, K2 = ~0ull, K3 = ~0ull;
    // word 0 (bits 1..63; bit 0 = top box, always kept)
#pragma unroll 16
    for (int b = 1; b < 64; ++b) {
      unsigned long long m0 = s_mask[(size_t)b * 4 + 0];
      unsigned long long sup = m0 & K0 & ((1ull << b) - 1ull);
      K0 = sup ? (K0 & ~(1ull << b)) : K0;
    }
    // word 1
#pragma unroll 16
    for (int b = 0; b < 64; ++b) {
      const unsigned long long* mi = &s_mask[(size_t)(64 + b) * 4];
      unsigned long long m0 = mi[0], m1 = mi[1];
      unsigned long long sup = (m0 & K0) | (m1 & K1 & ((1ull << b) - 1ull));
      K1 = sup ? (K1 & ~(1ull << b)) : K1;
    }
    // word 2
#pragma unroll 16
    for (int b = 0; b < 64; ++b) {
      const unsigned long long* mi = &s_mask[(size_t)(128 + b) * 4];
      unsigned long long m0 = mi[0], m1 = mi[1], m2 = mi[2];
      unsigned long long sup =
          (m0 & K0) | (m1 & K1) | (m2 & K2 & ((1ull << b) - 1ull));
      K2 = sup ? (K2 & ~(1ull << b)) : K2;
    }
    // word 3
#pragma unroll 16
    for (int b = 0; b < 64; ++b) {
      const unsigned long long* mi = &s_mask[(size_t)(192 + b) * 4];
      unsigned long long m0 = mi[0], m1 = mi[1], m2 = mi[2], m3 = mi[3];
      unsigned long long sup = (m0 & K0) | (m1 & K1) | (m2 & K2) |
                               (m3 & K3 & ((1ull << b) - 1ull));
      K3 = sup ? (K3 & ~(1ull << b)) : K3;
    }
    s_keep[0] = K0; s_keep[1] = K1; s_keep[2] = K2; s_keep[3] = K3;
  }
  __syncthreads();

  bool kept = false;
  if (q == 0) {
    int rk = s_rank[i];
    kept = ((s_keep[rk >> 6] >> (rk & 63)) & 1ull) && (mys > SCORE_TH_F);
    sm[i] = kept ? mys : -INFINITY;
  }
  __syncthreads();

  // top-100 rank over masked scores: float4 loads, 16/thread
  {
    float mym = sm[i];
    int cnt = 0;
#pragma unroll
    for (int j4 = j40; j4 < j40 + 16; ++j4) {
      float4 v = ((const float4*)sm)[j4];
      int jb = j4 * 4;
      cnt += (v.x > mym) || (v.x == mym && jb + 0 < i);
      cnt += (v.y > mym) || (v.y == mym && jb + 1 < i);
      cnt += (v.z > mym) || (v.z == mym && jb + 2 < i);
      cnt += (v.w > mym) || (v.w == mym && jb + 3 < i);
    }
    s_part[q * R_PROP + i] = cnt;
  }
  __syncthreads();

  if (q == 0) {
    int rk2 = s_part[i] + s_part[R_PROP + i] + s_part[2 * R_PROP + i] +
              s_part[3 * R_PROP + i];
    kept = kept && (rk2 < MAX_DET_I);
    float* dr = det + ((size_t)n * R_PROP + i) * 6;
    dr[0] = myb.x; dr[1] = myb.y; dr[2] = myb.z; dr[3] = myb.w;
    dr[4] = mys;
    dr[5] = kept ? 1.0f : 0.0f;
  }
}

// ---------------------------------------------------------------------------
extern "C" void kernel_launch(void* const* d_in, const int* in_sizes, int n_in,
                              void* d_out, int out_size, void* d_ws, size_t ws_size,
                              hipStream_t stream) {
  const float* features  = (const float*)d_in[0];  // (2,50,80,1024)
  const float* proposals = (const float*)d_in[1];  // (2,256,4)
  const float* gt_boxes  = (const float*)d_in[2];  // (2,64,4)
  // d_in[3] gt_classes: unused by reference outputs
  const float* W_cls = (const float*)d_in[4];      // (1024,81)
  const float* b_cls = (const float*)d_in[5];      // (81)
  const float* W_box = (const float*)d_in[6];      // (1024,4)
  const float* b_box = (const float*)d_in[7];      // (4)

  float* out = (float*)d_out;
  // out layout: det [0,3072) | matched_idxs [3072,3584) | match_labels [3584,4096)
  float* out_det = out;
  float* out_idx = out + N_IMG * R_PROP * 6;
  float* out_lbl = out_idx + N_IMG * R_PROP;

  // workspace layout
  float* feat_vec  = (float*)d_ws;                              // 512*1024
  float* boxes_dec = feat_vec + (size_t)N_IMG * R_PROP * C_CH;  // 512*4
  float* scores    = boxes_dec + (size_t)N_IMG * R_PROP * 4;    // 512

  match_kernel<<<2, 256, 0, stream>>>(proposals, gt_boxes, out_idx, out_lbl);
  roi_kernel<<<N_IMG * R_PROP, 1024, 0, stream>>>(features, proposals, feat_vec);
  heads_kernel<<<N_IMG * R_PROP, 512, 0, stream>>>(feat_vec, proposals, W_cls, b_cls,
                                                   W_box, b_box, boxes_dec, scores);
  nms_kernel<<<N_IMG, 1024, 0, stream>>>(boxes_dec, scores, out_det);
}

// Round 6
// 171.472 us; speedup vs baseline: 1.9505x; 1.0607x over previous
//
#include <hip/hip_runtime.h>
#include <math.h>

// Problem constants (from reference)
#define N_IMG 2
#define R_PROP 256
#define G_GT 64
#define C_CH 1024
#define FH 50
#define FW 80
#define P_POOL 14
#define NCLS 80
#define IMG_W_F 1280.0f
#define IMG_H_F 800.0f
#define SCALE_F 0.0625f
#define SCORE_TH_F 0.05f
#define NMS_TH_F 0.5f
#define IOU_TH_F 0.5f
#define MAX_DET_I 100
#define SCALE_CLAMP_F 4.135166556742356f  // log(1000/16)

// ---------------------------------------------------------------------------
// Kernel 0: rank proposals by y-center within each image -> perm
// perm[n*256 + rank] = within-image proposal index. One block, 512 threads.
// ---------------------------------------------------------------------------
__global__ __launch_bounds__(512) void sort_kernel(
    const float* __restrict__ proposals,  // (N,R,4)
    int* __restrict__ perm) {             // (N*R)
  const int t = threadIdx.x;      // 0..511 = n*256 + r
  const int n = t >> 8;
  __shared__ float cy[N_IMG * R_PROP];
  const float* pb = proposals + (size_t)t * 4;
  cy[t] = pb[1] + pb[3];          // 2*cy, monotone in cy
  __syncthreads();
  float my = cy[t];
  int rk = 0;
  const int base = n * R_PROP;
#pragma unroll 8
  for (int j = base; j < base + R_PROP; ++j) {
    float cj = cy[j];
    rk += (cj < my) || (cj == my && j < t);
  }
  perm[base + rk] = t & 255;
}

// ---------------------------------------------------------------------------
// Kernel 1: proposal<->gt matching (pairwise IoU argmax over gt axis)
// ---------------------------------------------------------------------------
__global__ __launch_bounds__(256) void match_kernel(
    const float* __restrict__ proposals,  // (N,R,4)
    const float* __restrict__ gt_boxes,   // (N,G,4)
    float* __restrict__ out_idx,          // (N,R) as float
    float* __restrict__ out_lbl) {        // (N,R) as float
  int t = blockIdx.x * blockDim.x + threadIdx.x;
  if (t >= N_IMG * R_PROP) return;
  int n = t / R_PROP;
  const float* pb = proposals + (size_t)t * 4;
  float bx1 = pb[0], by1 = pb[1], bx2 = pb[2], by2 = pb[3];
  float area_b = (bx2 - bx1) * (by2 - by1);
  float best = -1.0f;
  int bidx = 0;
  const float* gt = gt_boxes + (size_t)n * G_GT * 4;
#pragma unroll 4
  for (int g = 0; g < G_GT; ++g) {
    float gx1 = gt[g * 4 + 0], gy1 = gt[g * 4 + 1];
    float gx2 = gt[g * 4 + 2], gy2 = gt[g * 4 + 3];
    float area_a = (gx2 - gx1) * (gy2 - gy1);
    float ix1 = fmaxf(gx1, bx1), iy1 = fmaxf(gy1, by1);
    float ix2 = fminf(gx2, bx2), iy2 = fminf(gy2, by2);
    float iw = fmaxf(ix2 - ix1, 0.0f), ih = fmaxf(iy2 - iy1, 0.0f);
    float inter = iw * ih;
    float iou = inter / fmaxf(area_a + area_b - inter, 1e-9f);
    if (iou > best) { best = iou; bidx = g; }  // strict > keeps first occurrence
  }
  out_idx[t] = (float)bidx;
  out_lbl[t] = (best >= IOU_TH_F) ? 1.0f : 0.0f;
}

// ---------------------------------------------------------------------------
// Kernel 2: separable ROI-align + spatial mean -> feat_vec (N*R, C).
// 1024 threads/block, row-group split 4 ways (see R5). NEW: XCD-locality
// block swizzle — blockIdx maps to (xcd = b&7, slot = b>>3); XCD 0..3 get
// image 0's four y-bands (via perm, proposals y-sorted), XCD 4..7 image 1.
// All 64 blocks of a band co-resident on one XCD; band working set ~5 MB ~ L2.
// ---------------------------------------------------------------------------
__global__ __launch_bounds__(1024) void roi_kernel(
    const float* __restrict__ features,   // (N, FH, FW, C)
    const float* __restrict__ proposals,  // (N, R, 4)
    const int* __restrict__ perm,         // (N*R) y-sorted order
    float* __restrict__ feat_vec) {       // (N*R, C)
  const int b = blockIdx.x;
  const int xcd = b & 7;
  const int slot = b >> 3;              // 0..63
  const int n = xcd >> 2;               // image
  const int band = xcd & 3;
  const int blk = n * R_PROP + perm[n * R_PROP + band * 64 + slot];

  const float* feat = features + (size_t)n * (FH * FW * C_CH);
  const int t = threadIdx.x;
  const int c4 = t & 255;
  const int g = t >> 8;                 // 0..3 row group

  __shared__ float s_Wy[FH];
  __shared__ float s_Wx[FW];
  __shared__ int s_b[4];  // y_lo, y_hi, x_lo, x_hi
  __shared__ float4 s_red[3][256];

  if (t < FH) s_Wy[t] = 0.0f;
  if (t >= 128 && t < 128 + FW) s_Wx[t - 128] = 0.0f;
  __syncthreads();

  if (t < 2 * P_POOL) {
    const float* pb = proposals + (size_t)blk * 4;
    bool isY = t < P_POOL;
    int i = isY ? t : t - P_POOL;
    float lo = isY ? pb[1] : pb[0];
    float hi = isY ? pb[3] : pb[2];
    float limit = isY ? (float)(FH - 1) : (float)(FW - 1);
    float b1 = lo * SCALE_F, b2 = hi * SCALE_F;
    float bs = (b2 - b1) * (1.0f / P_POOL);
    float gg = b1 + ((float)i + 0.5f) * bs - 0.5f;
    gg = fminf(fmaxf(gg, 0.0f), limit);
    float fl = floorf(gg);
    int i0 = (int)fl;
    int i1 = min(i0 + 1, (int)limit);
    float l = gg - fl;
    if (isY) {
      atomicAdd(&s_Wy[i0], 1.0f - l);
      atomicAdd(&s_Wy[i1], l);
      if (i == 0) s_b[0] = i0;
      if (i == P_POOL - 1) s_b[1] = i1;
    } else {
      atomicAdd(&s_Wx[i0], 1.0f - l);
      atomicAdd(&s_Wx[i1], l);
      if (i == 0) s_b[2] = i0;
      if (i == P_POOL - 1) s_b[3] = i1;
    }
  }
  __syncthreads();

  const int ylo = s_b[0], yhi = s_b[1], xlo = s_b[2], xhi = s_b[3];
  float4 acc = make_float4(0.f, 0.f, 0.f, 0.f);
  for (int y = ylo + g; y <= yhi; y += 4) {
    float wy = s_Wy[y];
    const float4* row = (const float4*)(feat + (size_t)y * (FW * C_CH)) + c4;
#pragma unroll 8
    for (int x = xlo; x <= xhi; ++x) {
      float w = wy * s_Wx[x];
      float4 f = row[x * (C_CH / 4)];
      acc.x += w * f.x;
      acc.y += w * f.y;
      acc.z += w * f.z;
      acc.w += w * f.w;
    }
  }
  if (g > 0) s_red[g - 1][c4] = acc;
  __syncthreads();

  if (g == 0) {
    float4 a0 = s_red[0][c4];
    float4 a1 = s_red[1][c4];
    float4 a2 = s_red[2][c4];
    const float inv = 1.0f / (float)(P_POOL * P_POOL);
    float4 r;
    r.x = (acc.x + a0.x + a1.x + a2.x) * inv;
    r.y = (acc.y + a0.y + a1.y + a2.y) * inv;
    r.z = (acc.z + a0.z + a1.z + a2.z) * inv;
    r.w = (acc.w + a0.w + a1.w + a2.w) * inv;
    ((float4*)(feat_vec + (size_t)blk * C_CH))[c4] = r;
  }
}

// ---------------------------------------------------------------------------
// Kernel 3: linear heads + softmax fg-score + box decode. One block/proposal,
// 1024 threads, 12-way K-split (per-thread serial loads 171 -> ~86),
// shuffle-reduced softmax.
// ---------------------------------------------------------------------------
__global__ __launch_bounds__(1024) void heads_kernel(
    const float* __restrict__ feat_vec,   // (N*R, C)
    const float* __restrict__ proposals,  // (N, R, 4)
    const float* __restrict__ W_cls,      // (C, 81)
    const float* __restrict__ b_cls,      // (81)
    const float* __restrict__ W_box,      // (C, 4)
    const float* __restrict__ b_box,      // (4)
    float* __restrict__ boxes_dec,        // (N*R, 4)
    float* __restrict__ scores) {         // (N*R)
  const int blk = blockIdx.x;
  const int u = threadIdx.x;
  __shared__ float sf[C_CH];
  __shared__ float s_part[12][85];
  __shared__ float sl[85];
  __shared__ float s_red[8];

  // stage feat row: 1024 threads x 1 float
  sf[u] = feat_vec[(size_t)blk * C_CH + u];
  __syncthreads();

  const int kq = u / 85;        // 0..12 (u>=1020 -> 12, inactive)
  const int j = u - kq * 85;
  if (kq < 12) {
    float acc = 0.0f;
    if (j < 81) {
      const float* __restrict__ w = W_cls + j;
#pragma unroll 8
      for (int k = kq; k < C_CH; k += 12) acc += sf[k] * w[k * 81];
    } else {
      const float* __restrict__ w = W_box + (j - 81);
#pragma unroll 8
      for (int k = kq; k < C_CH; k += 12) acc += sf[k] * w[k * 4];
    }
    s_part[kq][j] = acc;
  }
  __syncthreads();

  if (u < 85) {
    float acc = (u < 81) ? b_cls[u] : b_box[u - 81];
#pragma unroll
    for (int p = 0; p < 12; ++p) acc += s_part[p][u];
    sl[u] = acc;
  }
  __syncthreads();

  // parallel reductions over the 81 logits (2 waves cover 0..127)
  if (u < 128) {
    float xm = (u < 81) ? sl[u] : -INFINITY;        // max over all 81
    float xf = (u < NCLS) ? sl[u] : -INFINITY;      // max over fg 80
#pragma unroll
    for (int off = 32; off; off >>= 1) {
      xm = fmaxf(xm, __shfl_down(xm, off, 64));
      xf = fmaxf(xf, __shfl_down(xf, off, 64));
    }
    if ((u & 63) == 0) { s_red[u >> 6] = xm; s_red[2 + (u >> 6)] = xf; }
  }
  __syncthreads();
  const float m = fmaxf(s_red[0], s_red[1]);
  if (u < 128) {
    float xs = (u < 81) ? expf(sl[u] - m) : 0.0f;
#pragma unroll
    for (int off = 32; off; off >>= 1) xs += __shfl_down(xs, off, 64);
    if ((u & 63) == 0) s_red[4 + (u >> 6)] = xs;
  }
  __syncthreads();

  if (u == 0) {
    float sum = s_red[4] + s_red[5];
    float fgm = fmaxf(s_red[2], s_red[3]);
    scores[blk] = expf(fgm - m) / sum;

    const float* pb = proposals + (size_t)blk * 4;
    float w = pb[2] - pb[0], h = pb[3] - pb[1];
    float cx = pb[0] + 0.5f * w, cy = pb[1] + 0.5f * h;
    float dx = sl[81] * 0.1f;
    float dy = sl[82] * 0.1f;
    float dw = fminf(sl[83] * 0.2f, SCALE_CLAMP_F);
    float dh = fminf(sl[84] * 0.2f, SCALE_CLAMP_F);
    float pcx = dx * w + cx, pcy = dy * h + cy;
    float pw = expf(dw) * w, ph = expf(dh) * h;
    float ox1 = fminf(fmaxf(pcx - 0.5f * pw, 0.0f), IMG_W_F);
    float oy1 = fminf(fmaxf(pcy - 0.5f * ph, 0.0f), IMG_H_F);
    float ox2 = fminf(fmaxf(pcx + 0.5f * pw, 0.0f), IMG_W_F);
    float oy2 = fminf(fmaxf(pcy + 0.5f * ph, 0.0f), IMG_H_F);
    float* bd = boxes_dec + (size_t)blk * 4;
    bd[0] = ox1; bd[1] = oy1; bd[2] = ox2; bd[3] = oy2;
  }
}

// ---------------------------------------------------------------------------
// Kernel 4: greedy NMS + score filter + top-100 rank + det write.
// One block per image, 1024 threads. Scans are 4-way split with float4 LDS
// loads; serial greedy pass is branchless with unconditional mask loads.
// ---------------------------------------------------------------------------
__global__ __launch_bounds__(1024) void nms_kernel(
    const float* __restrict__ boxes_dec,  // (N*R, 4)
    const float* __restrict__ scores,     // (N*R)
    float* __restrict__ det) {            // (N, R, 6)
  const int n = blockIdx.x;
  const int u = threadIdx.x;
  const int i = u & 255;
  const int q = u >> 8;           // 0..3
  const int j40 = q * 16;         // float4 index start for this quarter

  __shared__ __align__(16) float ss[R_PROP];     // scores, original order
  __shared__ float4 sbs[R_PROP];                 // sorted boxes
  __shared__ int s_part[4 * R_PROP];             // partial rank counts
  __shared__ int s_rank[R_PROP];
  __shared__ __align__(16) unsigned long long s_mask[R_PROP * 4];
  __shared__ unsigned long long s_keep[4];
  __shared__ __align__(16) float sm[R_PROP];     // masked scores, orig order

  float4 myb;
  float mys;
  if (q == 0) {
    myb = ((const float4*)boxes_dec)[n * R_PROP + i];
    mys = scores[n * R_PROP + i];
    ss[i] = mys;
  }
  __syncthreads();

  // stable descending rank (ties by original index): float4 loads, 16/thread
  {
    float s = ss[i];
    int cnt = 0;
#pragma unroll
    for (int j4 = j40; j4 < j40 + 16; ++j4) {
      float4 v = ((const float4*)ss)[j4];
      int jb = j4 * 4;
      cnt += (v.x > s) || (v.x == s && jb + 0 < i);
      cnt += (v.y > s) || (v.y == s && jb + 1 < i);
      cnt += (v.z > s) || (v.z == s && jb + 2 < i);
      cnt += (v.w > s) || (v.w == s && jb + 3 < i);
    }
    s_part[q * R_PROP + i] = cnt;
  }
  __syncthreads();
  if (q == 0) {
    int rk = s_part[i] + s_part[R_PROP + i] + s_part[2 * R_PROP + i] +
             s_part[3 * R_PROP + i];
    s_rank[i] = rk;
    sbs[rk] = myb;
  }
  __syncthreads();

  // phase 1: thread (i,q) computes mask word q of sorted box i vs sorted j
  {
    float4 bi = sbs[i];
    float area_i = (bi.z - bi.x) * (bi.w - bi.y);
    unsigned long long m = 0;
    const int j0 = q * 64;
#pragma unroll 8
    for (int jj = 0; jj < 64; ++jj) {
      float4 bj = sbs[j0 + jj];
      float area_j = (bj.z - bj.x) * (bj.w - bj.y);
      float ix1 = fmaxf(bi.x, bj.x), iy1 = fmaxf(bi.y, bj.y);
      float ix2 = fminf(bi.z, bj.z), iy2 = fminf(bi.w, bj.w);
      float iw = fmaxf(ix2 - ix1, 0.0f), ih = fmaxf(iy2 - iy1, 0.0f);
      float inter = iw * ih;
      float iou = inter / fmaxf(area_i + area_j - inter, 1e-9f);
      m |= (iou > NMS_TH_F) ? (1ull << jj) : 0ull;
    }
    s_mask[i * 4 + q] = m;
  }
  __syncthreads();

  // phase 2: branchless serial greedy pass over sorted order (thread 0).
  if (u == 0) {
    unsigned long long K0 = ~0ull, K1 = ~0ull, K2 = ~0ull, K3 = ~0ull;
    // word 0 (bits 1..63; bit 0 = top box, always kept)
#pragma unroll 16
    for (int b = 1; b < 64; ++b) {
      unsigned long long m0 = s_mask[(size_t)b * 4 + 0];
      unsigned long long sup = m0 & K0 & ((1ull << b) - 1ull);
      K0 = sup ? (K0 & ~(1ull << b)) : K0;
    }
    // word 1
#pragma unroll 16
    for (int b = 0; b < 64; ++b) {
      const unsigned long long* mi = &s_mask[(size_t)(64 + b) * 4];
      unsigned long long m0 = mi[0], m1 = mi[1];
      unsigned long long sup = (m0 & K0) | (m1 & K1 & ((1ull << b) - 1ull));
      K1 = sup ? (K1 & ~(1ull << b)) : K1;
    }
    // word 2
#pragma unroll 16
    for (int b = 0; b < 64; ++b) {
      const unsigned long long* mi = &s_mask[(size_t)(128 + b) * 4];
      unsigned long long m0 = mi[0], m1 = mi[1], m2 = mi[2];
      unsigned long long sup =
          (m0 & K0) | (m1 & K1) | (m2 & K2 & ((1ull << b) - 1ull));
      K2 = sup ? (K2 & ~(1ull << b)) : K2;
    }
    // word 3
#pragma unroll 16
    for (int b = 0; b < 64; ++b) {
      const unsigned long long* mi = &s_mask[(size_t)(192 + b) * 4];
      unsigned long long m0 = mi[0], m1 = mi[1], m2 = mi[2], m3 = mi[3];
      unsigned long long sup = (m0 & K0) | (m1 & K1) | (m2 & K2) |
                               (m3 & K3 & ((1ull << b) - 1ull));
      K3 = sup ? (K3 & ~(1ull << b)) : K3;
    }
    s_keep[0] = K0; s_keep[1] = K1; s_keep[2] = K2; s_keep[3] = K3;
  }
  __syncthreads();

  bool kept = false;
  if (q == 0) {
    int rk = s_rank[i];
    kept = ((s_keep[rk >> 6] >> (rk & 63)) & 1ull) && (mys > SCORE_TH_F);
    sm[i] = kept ? mys : -INFINITY;
  }
  __syncthreads();

  // top-100 rank over masked scores: float4 loads, 16/thread
  {
    float mym = sm[i];
    int cnt = 0;
#pragma unroll
    for (int j4 = j40; j4 < j40 + 16; ++j4) {
      float4 v = ((const float4*)sm)[j4];
      int jb = j4 * 4;
      cnt += (v.x > mym) || (v.x == mym && jb + 0 < i);
      cnt += (v.y > mym) || (v.y == mym && jb + 1 < i);
      cnt += (v.z > mym) || (v.z == mym && jb + 2 < i);
      cnt += (v.w > mym) || (v.w == mym && jb + 3 < i);
    }
    s_part[q * R_PROP + i] = cnt;
  }
  __syncthreads();

  if (q == 0) {
    int rk2 = s_part[i] + s_part[R_PROP + i] + s_part[2 * R_PROP + i] +
              s_part[3 * R_PROP + i];
    kept = kept && (rk2 < MAX_DET_I);
    float* dr = det + ((size_t)n * R_PROP + i) * 6;
    dr[0] = myb.x; dr[1] = myb.y; dr[2] = myb.z; dr[3] = myb.w;
    dr[4] = mys;
    dr[5] = kept ? 1.0f : 0.0f;
  }
}

// ---------------------------------------------------------------------------
extern "C" void kernel_launch(void* const* d_in, const int* in_sizes, int n_in,
                              void* d_out, int out_size, void* d_ws, size_t ws_size,
                              hipStream_t stream) {
  const float* features  = (const float*)d_in[0];  // (2,50,80,1024)
  const float* proposals = (const float*)d_in[1];  // (2,256,4)
  const float* gt_boxes  = (const float*)d_in[2];  // (2,64,4)
  // d_in[3] gt_classes: unused by reference outputs
  const float* W_cls = (const float*)d_in[4];      // (1024,81)
  const float* b_cls = (const float*)d_in[5];      // (81)
  const float* W_box = (const float*)d_in[6];      // (1024,4)
  const float* b_box = (const float*)d_in[7];      // (4)

  float* out = (float*)d_out;
  // out layout: det [0,3072) | matched_idxs [3072,3584) | match_labels [3584,4096)
  float* out_det = out;
  float* out_idx = out + N_IMG * R_PROP * 6;
  float* out_lbl = out_idx + N_IMG * R_PROP;

  // workspace layout
  float* feat_vec  = (float*)d_ws;                              // 512*1024
  float* boxes_dec = feat_vec + (size_t)N_IMG * R_PROP * C_CH;  // 512*4
  float* scores    = boxes_dec + (size_t)N_IMG * R_PROP * 4;    // 512
  int*   perm      = (int*)(scores + N_IMG * R_PROP);           // 512

  sort_kernel<<<1, 512, 0, stream>>>(proposals, perm);
  match_kernel<<<2, 256, 0, stream>>>(proposals, gt_boxes, out_idx, out_lbl);
  roi_kernel<<<N_IMG * R_PROP, 1024, 0, stream>>>(features, proposals, perm,
                                                  feat_vec);
  heads_kernel<<<N_IMG * R_PROP, 1024, 0, stream>>>(feat_vec, proposals, W_cls,
                                                    b_cls, W_box, b_box,
                                                    boxes_dec, scores);
  nms_kernel<<<N_IMG, 1024, 0, stream>>>(boxes_dec, scores, out_det);
}

// Round 7
// 167.798 us; speedup vs baseline: 1.9933x; 1.0219x over previous
//
#include <hip/hip_runtime.h>
#include <math.h>

// Problem constants (from reference)
#define N_IMG 2
#define R_PROP 256
#define G_GT 64
#define C_CH 1024
#define FH 50
#define FW 80
#define P_POOL 14
#define NCLS 80
#define IMG_W_F 1280.0f
#define IMG_H_F 800.0f
#define SCALE_F 0.0625f
#define SCORE_TH_F 0.05f
#define NMS_TH_F 0.5f
#define IOU_TH_F 0.5f
#define MAX_DET_I 100
#define SCALE_CLAMP_F 4.135166556742356f  // log(1000/16)

// ---------------------------------------------------------------------------
// Kernel 1 (prep): y-center sort (perm for XCD swizzle) + gt matching.
// One block, 512 threads; thread t = n*256 + r handles proposal t for both.
// ---------------------------------------------------------------------------
__global__ __launch_bounds__(512) void prep_kernel(
    const float* __restrict__ proposals,  // (N,R,4)
    const float* __restrict__ gt_boxes,   // (N,G,4)
    int* __restrict__ perm,               // (N*R)
    float* __restrict__ out_idx,          // (N,R) as float
    float* __restrict__ out_lbl) {        // (N,R) as float
  const int t = threadIdx.x;      // 0..511
  const int n = t >> 8;
  __shared__ float cy[N_IMG * R_PROP];
  const float* pb = proposals + (size_t)t * 4;
  float bx1 = pb[0], by1 = pb[1], bx2 = pb[2], by2 = pb[3];
  cy[t] = by1 + by2;              // 2*cy, monotone in cy
  __syncthreads();

  // y-rank within image
  {
    float my = cy[t];
    int rk = 0;
    const int base = n * R_PROP;
#pragma unroll 8
    for (int j = base; j < base + R_PROP; ++j) {
      float cj = cy[j];
      rk += (cj < my) || (cj == my && j < t);
    }
    perm[base + rk] = t & 255;
  }

  // gt matching
  {
    float area_b = (bx2 - bx1) * (by2 - by1);
    float best = -1.0f;
    int bidx = 0;
    const float* gt = gt_boxes + (size_t)n * G_GT * 4;
#pragma unroll 4
    for (int g = 0; g < G_GT; ++g) {
      float gx1 = gt[g * 4 + 0], gy1 = gt[g * 4 + 1];
      float gx2 = gt[g * 4 + 2], gy2 = gt[g * 4 + 3];
      float area_a = (gx2 - gx1) * (gy2 - gy1);
      float ix1 = fmaxf(gx1, bx1), iy1 = fmaxf(gy1, by1);
      float ix2 = fminf(gx2, bx2), iy2 = fminf(gy2, by2);
      float iw = fmaxf(ix2 - ix1, 0.0f), ih = fmaxf(iy2 - iy1, 0.0f);
      float inter = iw * ih;
      float iou = inter / fmaxf(area_a + area_b - inter, 1e-9f);
      if (iou > best) { best = iou; bidx = g; }
    }
    out_idx[t] = (float)bidx;
    out_lbl[t] = (best >= IOU_TH_F) ? 1.0f : 0.0f;
  }
}

// ---------------------------------------------------------------------------
// Kernel 2 (fused roi + heads): one block per proposal, 1024 threads.
// Phase 1: separable ROI-align + spatial mean -> feat row in LDS (no global
//          round-trip). XCD-locality swizzle via perm (proposals y-sorted;
//          XCD 0..3 = image 0 y-bands, XCD 4..7 = image 1).
// Phase 2: heads GEMV from LDS (12-way K-split), shuffle softmax, box decode.
// Heads' uniform small work hides inside roi's straggler slack (9..441 cells).
// ---------------------------------------------------------------------------
__global__ __launch_bounds__(1024) void roihead_kernel(
    const float* __restrict__ features,   // (N, FH, FW, C)
    const float* __restrict__ proposals,  // (N, R, 4)
    const int* __restrict__ perm,         // (N*R) y-sorted order
    const float* __restrict__ W_cls,      // (C, 81)
    const float* __restrict__ b_cls,      // (81)
    const float* __restrict__ W_box,      // (C, 4)
    const float* __restrict__ b_box,      // (4)
    float* __restrict__ boxes_dec,        // (N*R, 4)
    float* __restrict__ scores) {         // (N*R)
  const int b = blockIdx.x;
  const int xcd = b & 7;
  const int slot = b >> 3;              // 0..63
  const int n = xcd >> 2;               // image
  const int band = xcd & 3;
  const int blk = n * R_PROP + perm[n * R_PROP + band * 64 + slot];

  const float* feat = features + (size_t)n * (FH * FW * C_CH);
  const int t = threadIdx.x;
  const int c4 = t & 255;
  const int g = t >> 8;                 // 0..3 row group

  __shared__ float s_Wy[FH];
  __shared__ float s_Wx[FW];
  __shared__ int s_b[4];                // y_lo, y_hi, x_lo, x_hi
  __shared__ float4 s_red[3][256];
  __shared__ __align__(16) float sf[C_CH];
  __shared__ float s_part[12][85];
  __shared__ float sl[85];
  __shared__ float s_r2[8];

  if (t < FH) s_Wy[t] = 0.0f;
  if (t >= 128 && t < 128 + FW) s_Wx[t - 128] = 0.0f;
  __syncthreads();

  if (t < 2 * P_POOL) {
    const float* pb = proposals + (size_t)blk * 4;
    bool isY = t < P_POOL;
    int i = isY ? t : t - P_POOL;
    float lo = isY ? pb[1] : pb[0];
    float hi = isY ? pb[3] : pb[2];
    float limit = isY ? (float)(FH - 1) : (float)(FW - 1);
    float b1 = lo * SCALE_F, b2 = hi * SCALE_F;
    float bs = (b2 - b1) * (1.0f / P_POOL);
    float gg = b1 + ((float)i + 0.5f) * bs - 0.5f;
    gg = fminf(fmaxf(gg, 0.0f), limit);
    float fl = floorf(gg);
    int i0 = (int)fl;
    int i1 = min(i0 + 1, (int)limit);
    float l = gg - fl;
    if (isY) {
      atomicAdd(&s_Wy[i0], 1.0f - l);
      atomicAdd(&s_Wy[i1], l);
      if (i == 0) s_b[0] = i0;
      if (i == P_POOL - 1) s_b[1] = i1;
    } else {
      atomicAdd(&s_Wx[i0], 1.0f - l);
      atomicAdd(&s_Wx[i1], l);
      if (i == 0) s_b[2] = i0;
      if (i == P_POOL - 1) s_b[3] = i1;
    }
  }
  __syncthreads();

  // ---- phase 1: ROI accumulate (row groups of 4) ----
  {
    const int ylo = s_b[0], yhi = s_b[1], xlo = s_b[2], xhi = s_b[3];
    float4 acc = make_float4(0.f, 0.f, 0.f, 0.f);
    for (int y = ylo + g; y <= yhi; y += 4) {
      float wy = s_Wy[y];
      const float4* row = (const float4*)(feat + (size_t)y * (FW * C_CH)) + c4;
#pragma unroll 8
      for (int x = xlo; x <= xhi; ++x) {
        float w = wy * s_Wx[x];
        float4 f = row[x * (C_CH / 4)];
        acc.x += w * f.x;
        acc.y += w * f.y;
        acc.z += w * f.z;
        acc.w += w * f.w;
      }
    }
    if (g > 0) s_red[g - 1][c4] = acc;
    __syncthreads();
    if (g == 0) {
      float4 a0 = s_red[0][c4];
      float4 a1 = s_red[1][c4];
      float4 a2 = s_red[2][c4];
      const float inv = 1.0f / (float)(P_POOL * P_POOL);
      float4 r;
      r.x = (acc.x + a0.x + a1.x + a2.x) * inv;
      r.y = (acc.y + a0.y + a1.y + a2.y) * inv;
      r.z = (acc.z + a0.z + a1.z + a2.z) * inv;
      r.w = (acc.w + a0.w + a1.w + a2.w) * inv;
      ((float4*)sf)[c4] = r;
    }
    __syncthreads();
  }

  // ---- phase 2: heads GEMV from LDS, 12-way K-split ----
  const int kq = t / 85;        // 0..12 (t>=1020 -> 12, inactive)
  const int j = t - kq * 85;
  if (kq < 12) {
    float acc = 0.0f;
    if (j < 81) {
      const float* __restrict__ w = W_cls + j;
#pragma unroll 8
      for (int k = kq; k < C_CH; k += 12) acc += sf[k] * w[k * 81];
    } else {
      const float* __restrict__ w = W_box + (j - 81);
#pragma unroll 8
      for (int k = kq; k < C_CH; k += 12) acc += sf[k] * w[k * 4];
    }
    s_part[kq][j] = acc;
  }
  __syncthreads();

  if (t < 85) {
    float acc = (t < 81) ? b_cls[t] : b_box[t - 81];
#pragma unroll
    for (int p = 0; p < 12; ++p) acc += s_part[p][t];
    sl[t] = acc;
  }
  __syncthreads();

  // parallel reductions over the 81 logits (2 waves cover 0..127)
  if (t < 128) {
    float xm = (t < 81) ? sl[t] : -INFINITY;        // max over all 81
    float xf = (t < NCLS) ? sl[t] : -INFINITY;      // max over fg 80
#pragma unroll
    for (int off = 32; off; off >>= 1) {
      xm = fmaxf(xm, __shfl_down(xm, off, 64));
      xf = fmaxf(xf, __shfl_down(xf, off, 64));
    }
    if ((t & 63) == 0) { s_r2[t >> 6] = xm; s_r2[2 + (t >> 6)] = xf; }
  }
  __syncthreads();
  const float m = fmaxf(s_r2[0], s_r2[1]);
  if (t < 128) {
    float xs = (t < 81) ? expf(sl[t] - m) : 0.0f;
#pragma unroll
    for (int off = 32; off; off >>= 1) xs += __shfl_down(xs, off, 64);
    if ((t & 63) == 0) s_r2[4 + (t >> 6)] = xs;
  }
  __syncthreads();

  if (t == 0) {
    float sum = s_r2[4] + s_r2[5];
    float fgm = fmaxf(s_r2[2], s_r2[3]);
    scores[blk] = expf(fgm - m) / sum;

    const float* pb = proposals + (size_t)blk * 4;
    float w = pb[2] - pb[0], h = pb[3] - pb[1];
    float cx = pb[0] + 0.5f * w, cy = pb[1] + 0.5f * h;
    float dx = sl[81] * 0.1f;
    float dy = sl[82] * 0.1f;
    float dw = fminf(sl[83] * 0.2f, SCALE_CLAMP_F);
    float dh = fminf(sl[84] * 0.2f, SCALE_CLAMP_F);
    float pcx = dx * w + cx, pcy = dy * h + cy;
    float pw = expf(dw) * w, ph = expf(dh) * h;
    float ox1 = fminf(fmaxf(pcx - 0.5f * pw, 0.0f), IMG_W_F);
    float oy1 = fminf(fmaxf(pcy - 0.5f * ph, 0.0f), IMG_H_F);
    float ox2 = fminf(fmaxf(pcx + 0.5f * pw, 0.0f), IMG_W_F);
    float oy2 = fminf(fmaxf(pcy + 0.5f * ph, 0.0f), IMG_H_F);
    float* bd = boxes_dec + (size_t)blk * 4;
    bd[0] = ox1; bd[1] = oy1; bd[2] = ox2; bd[3] = oy2;
  }
}

// ---------------------------------------------------------------------------
// Kernel 3: greedy NMS + score filter + top-100 rank + det write.
// One block per image, 1024 threads. Scans are 4-way split with float4 LDS
// loads; serial greedy pass is branchless with unconditional mask loads.
// ---------------------------------------------------------------------------
__global__ __launch_bounds__(1024) void nms_kernel(
    const float* __restrict__ boxes_dec,  // (N*R, 4)
    const float* __restrict__ scores,     // (N*R)
    float* __restrict__ det) {            // (N, R, 6)
  const int n = blockIdx.x;
  const int u = threadIdx.x;
  const int i = u & 255;
  const int q = u >> 8;           // 0..3
  const int j40 = q * 16;         // float4 index start for this quarter

  __shared__ __align__(16) float ss[R_PROP];     // scores, original order
  __shared__ float4 sbs[R_PROP];                 // sorted boxes
  __shared__ int s_part[4 * R_PROP];             // partial rank counts
  __shared__ int s_rank[R_PROP];
  __shared__ __align__(16) unsigned long long s_mask[R_PROP * 4];
  __shared__ unsigned long long s_keep[4];
  __shared__ __align__(16) float sm[R_PROP];     // masked scores, orig order

  float4 myb;
  float mys;
  if (q == 0) {
    myb = ((const float4*)boxes_dec)[n * R_PROP + i];
    mys = scores[n * R_PROP + i];
    ss[i] = mys;
  }
  __syncthreads();

  // stable descending rank (ties by original index): float4 loads, 16/thread
  {
    float s = ss[i];
    int cnt = 0;
#pragma unroll
    for (int j4 = j40; j4 < j40 + 16; ++j4) {
      float4 v = ((const float4*)ss)[j4];
      int jb = j4 * 4;
      cnt += (v.x > s) || (v.x == s && jb + 0 < i);
      cnt += (v.y > s) || (v.y == s && jb + 1 < i);
      cnt += (v.z > s) || (v.z == s && jb + 2 < i);
      cnt += (v.w > s) || (v.w == s && jb + 3 < i);
    }
    s_part[q * R_PROP + i] = cnt;
  }
  __syncthreads();
  if (q == 0) {
    int rk = s_part[i] + s_part[R_PROP + i] + s_part[2 * R_PROP + i] +
             s_part[3 * R_PROP + i];
    s_rank[i] = rk;
    sbs[rk] = myb;
  }
  __syncthreads();

  // phase 1: thread (i,q) computes mask word q of sorted box i vs sorted j
  {
    float4 bi = sbs[i];
    float area_i = (bi.z - bi.x) * (bi.w - bi.y);
    unsigned long long m = 0;
    const int j0 = q * 64;
#pragma unroll 8
    for (int jj = 0; jj < 64; ++jj) {
      float4 bj = sbs[j0 + jj];
      float area_j = (bj.z - bj.x) * (bj.w - bj.y);
      float ix1 = fmaxf(bi.x, bj.x), iy1 = fmaxf(bi.y, bj.y);
      float ix2 = fminf(bi.z, bj.z), iy2 = fminf(bi.w, bj.w);
      float iw = fmaxf(ix2 - ix1, 0.0f), ih = fmaxf(iy2 - iy1, 0.0f);
      float inter = iw * ih;
      float iou = inter / fmaxf(area_i + area_j - inter, 1e-9f);
      m |= (iou > NMS_TH_F) ? (1ull << jj) : 0ull;
    }
    s_mask[i * 4 + q] = m;
  }
  __syncthreads();

  // phase 2: branchless serial greedy pass over sorted order (thread 0).
  if (u == 0) {
    unsigned long long K0 = ~0ull, K1 = ~0ull, K2 = ~0ull, K3 = ~0ull;
    // word 0 (bits 1..63; bit 0 = top box, always kept)
#pragma unroll 16
    for (int b = 1; b < 64; ++b) {
      unsigned long long m0 = s_mask[(size_t)b * 4 + 0];
      unsigned long long sup = m0 & K0 & ((1ull << b) - 1ull);
      K0 = sup ? (K0 & ~(1ull << b)) : K0;
    }
    // word 1
#pragma unroll 16
    for (int b = 0; b < 64; ++b) {
      const unsigned long long* mi = &s_mask[(size_t)(64 + b) * 4];
      unsigned long long m0 = mi[0], m1 = mi[1];
      unsigned long long sup = (m0 & K0) | (m1 & K1 & ((1ull << b) - 1ull));
      K1 = sup ? (K1 & ~(1ull << b)) : K1;
    }
    // word 2
#pragma unroll 16
    for (int b = 0; b < 64; ++b) {
      const unsigned long long* mi = &s_mask[(size_t)(128 + b) * 4];
      unsigned long long m0 = mi[0], m1 = mi[1], m2 = mi[2];
      unsigned long long sup =
          (m0 & K0) | (m1 & K1) | (m2 & K2 & ((1ull << b) - 1ull));
      K2 = sup ? (K2 & ~(1ull << b)) : K2;
    }
    // word 3
#pragma unroll 16
    for (int b = 0; b < 64; ++b) {
      const unsigned long long* mi = &s_mask[(size_t)(192 + b) * 4];
      unsigned long long m0 = mi[0], m1 = mi[1], m2 = mi[2], m3 = mi[3];
      unsigned long long sup = (m0 & K0) | (m1 & K1) | (m2 & K2) |
                               (m3 & K3 & ((1ull << b) - 1ull));
      K3 = sup ? (K3 & ~(1ull << b)) : K3;
    }
    s_keep[0] = K0; s_keep[1] = K1; s_keep[2] = K2; s_keep[3] = K3;
  }
  __syncthreads();

  bool kept = false;
  if (q == 0) {
    int rk = s_rank[i];
    kept = ((s_keep[rk >> 6] >> (rk & 63)) & 1ull) && (mys > SCORE_TH_F);
    sm[i] = kept ? mys : -INFINITY;
  }
  __syncthreads();

  // top-100 rank over masked scores: float4 loads, 16/thread
  {
    float mym = sm[i];
    int cnt = 0;
#pragma unroll
    for (int j4 = j40; j4 < j40 + 16; ++j4) {
      float4 v = ((const float4*)sm)[j4];
      int jb = j4 * 4;
      cnt += (v.x > mym) || (v.x == mym && jb + 0 < i);
      cnt += (v.y > mym) || (v.y == mym && jb + 1 < i);
      cnt += (v.z > mym) || (v.z == mym && jb + 2 < i);
      cnt += (v.w > mym) || (v.w == mym && jb + 3 < i);
    }
    s_part[q * R_PROP + i] = cnt;
  }
  __syncthreads();

  if (q == 0) {
    int rk2 = s_part[i] + s_part[R_PROP + i] + s_part[2 * R_PROP + i] +
              s_part[3 * R_PROP + i];
    kept = kept && (rk2 < MAX_DET_I);
    float* dr = det + ((size_t)n * R_PROP + i) * 6;
    dr[0] = myb.x; dr[1] = myb.y; dr[2] = myb.z; dr[3] = myb.w;
    dr[4] = mys;
    dr[5] = kept ? 1.0f : 0.0f;
  }
}

// ---------------------------------------------------------------------------
extern "C" void kernel_launch(void* const* d_in, const int* in_sizes, int n_in,
                              void* d_out, int out_size, void* d_ws, size_t ws_size,
                              hipStream_t stream) {
  const float* features  = (const float*)d_in[0];  // (2,50,80,1024)
  const float* proposals = (const float*)d_in[1];  // (2,256,4)
  const float* gt_boxes  = (const float*)d_in[2];  // (2,64,4)
  // d_in[3] gt_classes: unused by reference outputs
  const float* W_cls = (const float*)d_in[4];      // (1024,81)
  const float* b_cls = (const float*)d_in[5];      // (81)
  const float* W_box = (const float*)d_in[6];      // (1024,4)
  const float* b_box = (const float*)d_in[7];      // (4)

  float* out = (float*)d_out;
  // out layout: det [0,3072) | matched_idxs [3072,3584) | match_labels [3584,4096)
  float* out_det = out;
  float* out_idx = out + N_IMG * R_PROP * 6;
  float* out_lbl = out_idx + N_IMG * R_PROP;

  // workspace layout
  float* boxes_dec = (float*)d_ws;                              // 512*4
  float* scores    = boxes_dec + (size_t)N_IMG * R_PROP * 4;    // 512
  int*   perm      = (int*)(scores + N_IMG * R_PROP);           // 512

  prep_kernel<<<1, 512, 0, stream>>>(proposals, gt_boxes, perm, out_idx, out_lbl);
  roihead_kernel<<<N_IMG * R_PROP, 1024, 0, stream>>>(
      features, proposals, perm, W_cls, b_cls, W_box, b_box, boxes_dec, scores);
  nms_kernel<<<N_IMG, 1024, 0, stream>>>(boxes_dec, scores, out_det);
}